// Round 5
// baseline (7138.763 us; speedup 1.0000x reference)
//
#include <hip/hip_runtime.h>
#include <cstdint>

typedef unsigned short ushort_t;
typedef __attribute__((ext_vector_type(8))) short short8;
typedef __attribute__((ext_vector_type(4))) float f32x4;
typedef unsigned long long u64;

#define T_STEPS 512
#define BATCH   64
#define IDIM    512
#define HIDDEN  1024
#define NWGP    32          // persistent workgroups
#define NC      32          // output columns per WG
#define BH      (BATCH*HIDDEN)   // 65536
#define STW     65536       // ushort index where per-wave scr begins

__device__ __forceinline__ ushort_t f2bf(float f) {
  unsigned int x = __float_as_uint(f);
  unsigned int r = (x + 0x7fffu + ((x >> 16) & 1u)) >> 16;
  return (ushort_t)r;
}
__device__ __forceinline__ float sigmoid_f(float x) { return 1.f / (1.f + __expf(-x)); }
__device__ __forceinline__ float tanh_f(float x)    { return 1.f - 2.f / (1.f + __expf(2.f * x)); }

// ---- coherent register load: bypass L1+L2, read at LLC ----
#define ALOAD(D, P, OFF) \
  asm volatile("global_load_dwordx4 %0, %1, off offset:" #OFF " sc0 sc1" \
               : "=v"(D) : "v"(P) : "memory")
#define WAITV(N) asm volatile("s_waitcnt vmcnt(" #N ")" ::: "memory")

#define ISSUE32(P) do { \
  ALOAD(a[0],P,0);     ALOAD(a[1],P,64);    ALOAD(a[2],P,128);   ALOAD(a[3],P,192);  \
  ALOAD(a[4],P,256);   ALOAD(a[5],P,320);   ALOAD(a[6],P,384);   ALOAD(a[7],P,448);  \
  ALOAD(a[8],P,512);   ALOAD(a[9],P,576);   ALOAD(a[10],P,640);  ALOAD(a[11],P,704); \
  ALOAD(a[12],P,768);  ALOAD(a[13],P,832);  ALOAD(a[14],P,896);  ALOAD(a[15],P,960); \
  ALOAD(a[16],P,1024); ALOAD(a[17],P,1088); ALOAD(a[18],P,1152); ALOAD(a[19],P,1216);\
  ALOAD(a[20],P,1280); ALOAD(a[21],P,1344); ALOAD(a[22],P,1408); ALOAD(a[23],P,1472);\
  ALOAD(a[24],P,1536); ALOAD(a[25],P,1600); ALOAD(a[26],P,1664); ALOAD(a[27],P,1728);\
  ALOAD(a[28],P,1792); ALOAD(a[29],P,1856); ALOAD(a[30],P,1920); ALOAD(a[31],P,1984);\
} while (0)

#define KSTEP(J, VN, WOFF, A0, A1) do { \
  WAITV(VN); \
  __builtin_amdgcn_sched_barrier(0); \
  const int k0_ = (J) * 64 + koff; \
  short8 b00_ = *(const short8*)&smem[(WOFF) + wb0 + (k0_ ^ sz0)]; \
  short8 b10_ = *(const short8*)&smem[(WOFF) + wb1 + (k0_ ^ sz1)]; \
  short8 b01_ = *(const short8*)&smem[(WOFF) + wb0 + ((k0_ + 32) ^ sz0)]; \
  short8 b11_ = *(const short8*)&smem[(WOFF) + wb1 + ((k0_ + 32) ^ sz1)]; \
  A0 = __builtin_amdgcn_mfma_f32_16x16x32_bf16(a[2*(J)],   b00_, A0, 0, 0, 0); \
  A1 = __builtin_amdgcn_mfma_f32_16x16x32_bf16(a[2*(J)],   b10_, A1, 0, 0, 0); \
  A0 = __builtin_amdgcn_mfma_f32_16x16x32_bf16(a[2*(J)+1], b01_, A0, 0, 0, 0); \
  A1 = __builtin_amdgcn_mfma_f32_16x16x32_bf16(a[2*(J)+1], b11_, A1, 0, 0, 0); \
} while (0)

#define MATVEC16(WOFF, A0, A1) do { \
  KSTEP(0,30,WOFF,A0,A1);  KSTEP(1,28,WOFF,A0,A1);  KSTEP(2,26,WOFF,A0,A1);  KSTEP(3,24,WOFF,A0,A1); \
  KSTEP(4,22,WOFF,A0,A1);  KSTEP(5,20,WOFF,A0,A1);  KSTEP(6,18,WOFF,A0,A1);  KSTEP(7,16,WOFF,A0,A1); \
  KSTEP(8,14,WOFF,A0,A1);  KSTEP(9,12,WOFF,A0,A1);  KSTEP(10,10,WOFF,A0,A1); KSTEP(11,8,WOFF,A0,A1); \
  KSTEP(12,6,WOFF,A0,A1);  KSTEP(13,4,WOFF,A0,A1);  KSTEP(14,2,WOFF,A0,A1);  KSTEP(15,0,WOFF,A0,A1); \
} while (0)

// ---------------- weight conversion: f32 -> bf16, split h-part / x-part ----
__global__ __launch_bounds__(256) void convert_weights(
    const float* __restrict__ Wz, const float* __restrict__ Wh,
    ushort_t* __restrict__ Wzh, ushort_t* __restrict__ Wzx,
    ushort_t* __restrict__ Whh, ushort_t* __restrict__ Whx)
{
  int j = blockIdx.x;
  const float* W = blockIdx.y ? Wh : Wz;
  ushort_t* Bh = blockIdx.y ? Whh : Wzh;
  ushort_t* Bx = blockIdx.y ? Whx : Wzx;
  const float* row = W + (size_t)j * (HIDDEN + IDIM);
  for (int c = threadIdx.x; c < HIDDEN + IDIM; c += 256) {
    ushort_t v = f2bf(row[c]);
    if (c < HIDDEN) Bh[(size_t)j * HIDDEN + c] = v;
    else            Bx[(size_t)j * IDIM + (c - HIDDEN)] = v;
  }
}

// ---------------- phase 1: Gx = x @ Wx^T + b  (two GEMMs via blockIdx.z) ----
__global__ __launch_bounds__(256) void gx_gemm(
    const float* __restrict__ x,
    const ushort_t* __restrict__ Wzx, const ushort_t* __restrict__ Whx,
    const float* __restrict__ bz, const float* __restrict__ bh,
    float* __restrict__ outZ, float* __restrict__ outR)
{
  const int which = blockIdx.z;
  const ushort_t* W = which ? Whx : Wzx;
  const float* bias = which ? bh : bz;
  float* out = which ? outR : outZ;
  const int m0 = blockIdx.x * 64;
  const int n0 = blockIdx.y * 64;
  __shared__ ushort_t As[64 * 40];
  __shared__ ushort_t Bs[64 * 40];
  const int tid = threadIdx.x;
  const int lane = tid & 63, w4 = tid >> 6;
  const int row = tid >> 2, q = tid & 3;
  f32x4 acc[4] = {{0,0,0,0},{0,0,0,0},{0,0,0,0},{0,0,0,0}};
  for (int kk = 0; kk < IDIM; kk += 32) {
    const float* xs = &x[(size_t)(m0 + row) * IDIM + kk + q * 8];
    float4 f0 = *(const float4*)xs;
    float4 f1 = *(const float4*)(xs + 4);
    short8 av;
    av[0]=f2bf(f0.x); av[1]=f2bf(f0.y); av[2]=f2bf(f0.z); av[3]=f2bf(f0.w);
    av[4]=f2bf(f1.x); av[5]=f2bf(f1.y); av[6]=f2bf(f1.z); av[7]=f2bf(f1.w);
    short8 bv = *(const short8*)&W[(size_t)(n0 + row) * IDIM + kk + q * 8];
    __syncthreads();
    *(short8*)&As[row * 40 + q * 8] = av;
    *(short8*)&Bs[row * 40 + q * 8] = bv;
    __syncthreads();
    short8 af = *(const short8*)&As[(w4 * 16 + (lane & 15)) * 40 + (lane >> 4) * 8];
    #pragma unroll
    for (int c = 0; c < 4; ++c) {
      short8 bf = *(const short8*)&Bs[(c * 16 + (lane & 15)) * 40 + (lane >> 4) * 8];
      acc[c] = __builtin_amdgcn_mfma_f32_16x16x32_bf16(af, bf, acc[c], 0, 0, 0);
    }
  }
  #pragma unroll
  for (int c = 0; c < 4; ++c) {
    int j = n0 + c * 16 + (lane & 15);
    float bv = bias[j];
    #pragma unroll
    for (int r = 0; r < 4; ++r) {
      int m = m0 + w4 * 16 + (lane >> 4) * 4 + r;
      out[(size_t)m * HIDDEN + j] = acc[c][r] + bv;
    }
  }
}

// ---------------- persistent recurrent kernel ------------------------------
// Wave-autonomous: per-wave flags (no RMW, no __syncthreads in loop).
// A-operand: 32 coherent global_load_dwordx4 into VGPRs, counted vmcnt.
__global__ __launch_bounds__(256) void gru_persist(
    const ushort_t* __restrict__ Wzh, const ushort_t* __restrict__ Whh,
    float* __restrict__ H, float* __restrict__ Z, float* __restrict__ R,
    u64* __restrict__ h_buf, u64* __restrict__ ghb, int* __restrict__ flags)
{
  extern __shared__ ushort_t smem[];   // [0,32768) Wz, [32768,65536) Wh, [STW,..) scr
  const int w = blockIdx.x;
  const int tid = threadIdx.x;
  const int lane = tid & 63, wv = tid >> 6;
  const int jbase = w * NC;
  const int li = lane & 15, q4 = lane >> 4;
  const int R0 = wv * 16;
  const ushort_t* hgu = (const ushort_t*)h_buf;
  const ushort_t* ggu = (const ushort_t*)ghb;

  // stage weight slices (row-XOR swizzle k ^= (row&7)<<3 for conflict-free B reads)
  for (int c = tid; c < NC * 128; c += 256) {
    int row = c >> 7, k8 = (c & 127) * 8;
    int dst = row * 1024 + (k8 ^ ((row & 7) << 3));
    *(short8*)&smem[dst]         = *(const short8*)&Wzh[(size_t)(jbase + row) * 1024 + k8];
    *(short8*)&smem[32768 + dst] = *(const short8*)&Whh[(size_t)(jbase + row) * 1024 + k8];
  }
  __syncthreads();   // weights ready (h0 + flags zeroed by host memset)

  // H[0] = 0 (bulk, background)
  { const int srow = tid >> 2, scc = (tid & 3) * 8;
    float4 z4 = {0.f, 0.f, 0.f, 0.f};
    *(float4*)&H[(size_t)srow * 1024 + jbase + scc]     = z4;
    *(float4*)&H[(size_t)srow * 1024 + jbase + scc + 4] = z4; }

  // per-thread constants
  const int wb0 = li * 1024,     wb1 = (16 + li) * 1024;
  const int sz0 = (li & 7) << 3, sz1 = ((16 + li) & 7) << 3;
  const int koff = q4 * 8;
  const int m0 = wv * 16 + q4 * 4;
  const int sb = STW + wv * 640;                 // per-wave scr [16][40] ushort
  const int str0 = lane >> 3, stc = lane & 7;
  const int gi0 = ((R0 + str0) * 1024 + jbase + stc * 4) >> 2;       // u64 idx
  const int gi1 = ((R0 + 8 + str0) * 1024 + jbase + stc * 4) >> 2;
  const int scr0 = sb + str0 * 40 + stc * 4;
  const int scr1 = sb + (8 + str0) * 40 + stc * 4;
  const ushort_t* gAh = hgu + (size_t)(R0 + li) * 1024 + koff;
  const ushort_t* gAg = ggu + (size_t)(R0 + li) * 1024 + koff;
  int* myflag = flags + (w * 4 + wv) * 16;       // 64B-spaced per-wave flags
  const int f0a = lane * 16, f1a = (lane + 64) * 16;

  float hreg[2][4] = {{0.f,0.f,0.f,0.f},{0.f,0.f,0.f,0.f}};
  short8 a[32];

  for (int t = 0; t < T_STEPS; ++t) {
    const size_t zoff = (size_t)t * BH;

    // ---- phase A: z-gate -------------------------------------------------
    float gz[2][4];
    #pragma unroll
    for (int c = 0; c < 2; ++c)
      #pragma unroll
      for (int r = 0; r < 4; ++r)
        gz[c][r] = Z[zoff + (size_t)(m0 + r) * 1024 + jbase + c * 16 + li];

    { const int tgt = 2 * t;          // all waves finished h(t) stores
      for (;;) {
        int f0 = __hip_atomic_load(flags + f0a, __ATOMIC_RELAXED, __HIP_MEMORY_SCOPE_AGENT);
        int f1 = __hip_atomic_load(flags + f1a, __ATOMIC_RELAXED, __HIP_MEMORY_SCOPE_AGENT);
        if (__all((f0 < f1 ? f0 : f1) >= tgt)) break;
      } }
    // poll's last atomic-load wait leaves vmcnt==0 -> counted waits exact

    f32x4 acc0 = {0,0,0,0}, acc1 = {0,0,0,0};
    ISSUE32(gAh);
    MATVEC16(0, acc0, acc1);

    float g[2][4];
    #pragma unroll
    for (int c = 0; c < 2; ++c)
      #pragma unroll
      for (int r = 0; r < 4; ++r) {
        g[c][r] = sigmoid_f((c ? acc1[r] : acc0[r]) + gz[c][r]);
        smem[sb + (q4 * 4 + r) * 40 + c * 16 + li] = f2bf(g[c][r] * hreg[c][r]);
      }
    asm volatile("s_waitcnt lgkmcnt(0)" ::: "memory");
    __builtin_amdgcn_sched_barrier(0);
    { u64 v0 = *(const u64*)&smem[scr0];
      u64 v1 = *(const u64*)&smem[scr1];
      __hip_atomic_store(ghb + gi0, v0, __ATOMIC_RELAXED, __HIP_MEMORY_SCOPE_AGENT);
      __hip_atomic_store(ghb + gi1, v1, __ATOMIC_RELAXED, __HIP_MEMORY_SCOPE_AGENT); }
    WAITV(0);                          // g*h stores acked at LLC
    __hip_atomic_store(myflag, 2 * t + 1, __ATOMIC_RELAXED, __HIP_MEMORY_SCOPE_AGENT);

    // ---- phase B: candidate ---------------------------------------------
    float gh[2][4];
    #pragma unroll
    for (int c = 0; c < 2; ++c)
      #pragma unroll
      for (int r = 0; r < 4; ++r)
        gh[c][r] = R[zoff + (size_t)(m0 + r) * 1024 + jbase + c * 16 + li];

    { const int tgt = 2 * t + 1;      // all waves finished g*h stores
      for (;;) {
        int f0 = __hip_atomic_load(flags + f0a, __ATOMIC_RELAXED, __HIP_MEMORY_SCOPE_AGENT);
        int f1 = __hip_atomic_load(flags + f1a, __ATOMIC_RELAXED, __HIP_MEMORY_SCOPE_AGENT);
        if (__all((f0 < f1 ? f0 : f1) >= tgt)) break;
      } }

    f32x4 acc2 = {0,0,0,0}, acc3 = {0,0,0,0};
    ISSUE32(gAg);
    MATVEC16(32768, acc2, acc3);

    float hn[2][4];
    #pragma unroll
    for (int c = 0; c < 2; ++c)
      #pragma unroll
      for (int r = 0; r < 4; ++r) {
        float cand = tanh_f((c ? acc3[r] : acc2[r]) + gh[c][r]);
        float v = (1.f - g[c][r]) * hreg[c][r] + g[c][r] * cand;
        hreg[c][r] = v;
        hn[c][r] = v;
        smem[sb + (q4 * 4 + r) * 40 + c * 16 + li] = f2bf(v);
      }
    asm volatile("s_waitcnt lgkmcnt(0)" ::: "memory");
    __builtin_amdgcn_sched_barrier(0);
    { u64 v0 = *(const u64*)&smem[scr0];
      u64 v1 = *(const u64*)&smem[scr1];
      __hip_atomic_store(h_buf + gi0, v0, __ATOMIC_RELAXED, __HIP_MEMORY_SCOPE_AGENT);
      __hip_atomic_store(h_buf + gi1, v1, __ATOMIC_RELAXED, __HIP_MEMORY_SCOPE_AGENT); }
    WAITV(0);                          // h stores acked at LLC
    __hip_atomic_store(myflag, 2 * t + 2, __ATOMIC_RELAXED, __HIP_MEMORY_SCOPE_AGENT);

    // bulk outputs (plain stores, drain in background during next poll)
    const size_t hoff = (size_t)(t + 1) * BH;
    #pragma unroll
    for (int c = 0; c < 2; ++c)
      #pragma unroll
      for (int r = 0; r < 4; ++r) {
        const size_t rowo = (size_t)(m0 + r) * 1024 + jbase + c * 16 + li;
        Z[zoff + rowo] = g[c][r];
        R[zoff + rowo] = g[c][r];
        H[hoff + rowo] = hn[c][r];
      }
  }
}

// ---------------- host launcher -------------------------------------------
extern "C" void kernel_launch(void* const* d_in, const int* in_sizes, int n_in,
                              void* d_out, int out_size, void* d_ws, size_t ws_size,
                              hipStream_t stream) {
  (void)in_sizes; (void)n_in; (void)out_size; (void)ws_size;
  const float* x  = (const float*)d_in[0];
  const float* Wz = (const float*)d_in[1];
  const float* bz = (const float*)d_in[2];
  const float* Wh = (const float*)d_in[3];
  const float* bh = (const float*)d_in[4];

  float* H = (float*)d_out;
  float* Z = H + (size_t)(T_STEPS + 1) * BH;
  float* R = Z + (size_t)T_STEPS * BH;

  char* ws = (char*)d_ws;
  int*      flags = (int*)ws;                                   // 8 KB (128 x 64B)
  u64*      h_buf = (u64*)(ws + 16384);                         // 128 KB linear bf16
  u64*      ghb   = (u64*)(ws + 16384 + 131072);                // 128 KB linear bf16
  ushort_t* Wzh   = (ushort_t*)(ws + 16384 + 2 * 131072);       // 2 MB
  ushort_t* Whh   = Wzh + (size_t)HIDDEN * HIDDEN;              // 2 MB
  ushort_t* Wzx   = Whh + (size_t)HIDDEN * HIDDEN;              // 1 MB
  ushort_t* Whx   = Wzx + (size_t)HIDDEN * IDIM;                // 1 MB

  hipFuncSetAttribute((const void*)gru_persist,
                      hipFuncAttributeMaxDynamicSharedMemorySize, 136192);

  hipMemsetAsync(flags, 0, 8192, stream);
  hipMemsetAsync(h_buf, 0, 131072, stream);   // h0 = 0 (kernel-boundary visible)
  convert_weights<<<dim3(HIDDEN, 2), 256, 0, stream>>>(Wz, Wh, Wzh, Wzx, Whh, Whx);
  gx_gemm<<<dim3(T_STEPS * BATCH / 64, HIDDEN / 64, 2), 256, 0, stream>>>(
      x, Wzx, Whx, bz, bh, Z, R);
  gru_persist<<<NWGP, 256, 136192, stream>>>(Wzh, Whh, H, Z, R, h_buf, ghb, flags);
}

// Round 6
// 6202.478 us; speedup vs baseline: 1.1510x; 1.1510x over previous
//
#include <hip/hip_runtime.h>
#include <cstdint>

typedef unsigned short ushort_t;
typedef __attribute__((ext_vector_type(8))) short short8;
typedef __attribute__((ext_vector_type(4))) float f32x4;
typedef unsigned long long u64;

#define T_STEPS 512
#define BATCH   64
#define IDIM    512
#define HIDDEN  1024
#define NWGP    32          // persistent workgroups
#define NC      32          // output columns per WG
#define BH      (BATCH*HIDDEN)   // 65536
#define STW     65536       // ushort index where per-wave scr begins

__device__ __forceinline__ ushort_t f2bf(float f) {
  unsigned int x = __float_as_uint(f);
  unsigned int r = (x + 0x7fffu + ((x >> 16) & 1u)) >> 16;
  return (ushort_t)r;
}
__device__ __forceinline__ float sigmoid_f(float x) { return 1.f / (1.f + __expf(-x)); }
__device__ __forceinline__ float tanh_f(float x)    { return 1.f - 2.f / (1.f + __expf(2.f * x)); }

// ---- coherent register load: bypass L1+L2, read at LLC ----
#define ALOAD(D, P, OFF) \
  asm volatile("global_load_dwordx4 %0, %1, off offset:" #OFF " sc0 sc1" \
               : "=v"(D) : "v"(P) : "memory")
#define WAITV(N) asm volatile("s_waitcnt vmcnt(" #N ")" ::: "memory")

#define ISSUE32(P) do { \
  ALOAD(a[0],P,0);     ALOAD(a[1],P,64);    ALOAD(a[2],P,128);   ALOAD(a[3],P,192);  \
  ALOAD(a[4],P,256);   ALOAD(a[5],P,320);   ALOAD(a[6],P,384);   ALOAD(a[7],P,448);  \
  ALOAD(a[8],P,512);   ALOAD(a[9],P,576);   ALOAD(a[10],P,640);  ALOAD(a[11],P,704); \
  ALOAD(a[12],P,768);  ALOAD(a[13],P,832);  ALOAD(a[14],P,896);  ALOAD(a[15],P,960); \
  ALOAD(a[16],P,1024); ALOAD(a[17],P,1088); ALOAD(a[18],P,1152); ALOAD(a[19],P,1216);\
  ALOAD(a[20],P,1280); ALOAD(a[21],P,1344); ALOAD(a[22],P,1408); ALOAD(a[23],P,1472);\
  ALOAD(a[24],P,1536); ALOAD(a[25],P,1600); ALOAD(a[26],P,1664); ALOAD(a[27],P,1728);\
  ALOAD(a[28],P,1792); ALOAD(a[29],P,1856); ALOAD(a[30],P,1920); ALOAD(a[31],P,1984);\
} while (0)

// B ds_reads issue BEFORE the vmcnt wait (overlap LDS reads with LLC latency)
#define KSTEP(J, VN, WOFF, A0, A1) do { \
  const int k0_ = (J) * 64 + koff; \
  short8 b00_ = *(const short8*)&smem[(WOFF) + wb0 + (k0_ ^ sz0)]; \
  short8 b10_ = *(const short8*)&smem[(WOFF) + wb1 + (k0_ ^ sz1)]; \
  short8 b01_ = *(const short8*)&smem[(WOFF) + wb0 + ((k0_ + 32) ^ sz0)]; \
  short8 b11_ = *(const short8*)&smem[(WOFF) + wb1 + ((k0_ + 32) ^ sz1)]; \
  WAITV(VN); \
  __builtin_amdgcn_sched_barrier(0); \
  A0 = __builtin_amdgcn_mfma_f32_16x16x32_bf16(a[2*(J)],   b00_, A0, 0, 0, 0); \
  A1 = __builtin_amdgcn_mfma_f32_16x16x32_bf16(a[2*(J)],   b10_, A1, 0, 0, 0); \
  A0 = __builtin_amdgcn_mfma_f32_16x16x32_bf16(a[2*(J)+1], b01_, A0, 0, 0, 0); \
  A1 = __builtin_amdgcn_mfma_f32_16x16x32_bf16(a[2*(J)+1], b11_, A1, 0, 0, 0); \
} while (0)

#define MATVEC16(WOFF, A0, A1) do { \
  KSTEP(0,30,WOFF,A0,A1);  KSTEP(1,28,WOFF,A0,A1);  KSTEP(2,26,WOFF,A0,A1);  KSTEP(3,24,WOFF,A0,A1); \
  KSTEP(4,22,WOFF,A0,A1);  KSTEP(5,20,WOFF,A0,A1);  KSTEP(6,18,WOFF,A0,A1);  KSTEP(7,16,WOFF,A0,A1); \
  KSTEP(8,14,WOFF,A0,A1);  KSTEP(9,12,WOFF,A0,A1);  KSTEP(10,10,WOFF,A0,A1); KSTEP(11,8,WOFF,A0,A1); \
  KSTEP(12,6,WOFF,A0,A1);  KSTEP(13,4,WOFF,A0,A1);  KSTEP(14,2,WOFF,A0,A1);  KSTEP(15,0,WOFF,A0,A1); \
} while (0)

// single-poller barrier wait: 32 pollers total, one LLC line, broadcast via barrier
__device__ __forceinline__ void poll_ctr(int* ctr, int target) {
  if (threadIdx.x == 0) {
    while (__hip_atomic_load(ctr, __ATOMIC_RELAXED, __HIP_MEMORY_SCOPE_AGENT) < target)
      __builtin_amdgcn_s_sleep(1);
  }
  __syncthreads();
}

// ---------------- weight conversion: f32 -> bf16, split h-part / x-part ----
__global__ __launch_bounds__(256) void convert_weights(
    const float* __restrict__ Wz, const float* __restrict__ Wh,
    ushort_t* __restrict__ Wzh, ushort_t* __restrict__ Wzx,
    ushort_t* __restrict__ Whh, ushort_t* __restrict__ Whx)
{
  int j = blockIdx.x;
  const float* W = blockIdx.y ? Wh : Wz;
  ushort_t* Bh = blockIdx.y ? Whh : Wzh;
  ushort_t* Bx = blockIdx.y ? Whx : Wzx;
  const float* row = W + (size_t)j * (HIDDEN + IDIM);
  for (int c = threadIdx.x; c < HIDDEN + IDIM; c += 256) {
    ushort_t v = f2bf(row[c]);
    if (c < HIDDEN) Bh[(size_t)j * HIDDEN + c] = v;
    else            Bx[(size_t)j * IDIM + (c - HIDDEN)] = v;
  }
}

// ---------------- phase 1: Gx = x @ Wx^T + b  (two GEMMs via blockIdx.z) ----
__global__ __launch_bounds__(256) void gx_gemm(
    const float* __restrict__ x,
    const ushort_t* __restrict__ Wzx, const ushort_t* __restrict__ Whx,
    const float* __restrict__ bz, const float* __restrict__ bh,
    float* __restrict__ outZ, float* __restrict__ outR)
{
  const int which = blockIdx.z;
  const ushort_t* W = which ? Whx : Wzx;
  const float* bias = which ? bh : bz;
  float* out = which ? outR : outZ;
  const int m0 = blockIdx.x * 64;
  const int n0 = blockIdx.y * 64;
  __shared__ ushort_t As[64 * 40];
  __shared__ ushort_t Bs[64 * 40];
  const int tid = threadIdx.x;
  const int lane = tid & 63, w4 = tid >> 6;
  const int row = tid >> 2, q = tid & 3;
  f32x4 acc[4] = {{0,0,0,0},{0,0,0,0},{0,0,0,0},{0,0,0,0}};
  for (int kk = 0; kk < IDIM; kk += 32) {
    const float* xs = &x[(size_t)(m0 + row) * IDIM + kk + q * 8];
    float4 f0 = *(const float4*)xs;
    float4 f1 = *(const float4*)(xs + 4);
    short8 av;
    av[0]=f2bf(f0.x); av[1]=f2bf(f0.y); av[2]=f2bf(f0.z); av[3]=f2bf(f0.w);
    av[4]=f2bf(f1.x); av[5]=f2bf(f1.y); av[6]=f2bf(f1.z); av[7]=f2bf(f1.w);
    short8 bv = *(const short8*)&W[(size_t)(n0 + row) * IDIM + kk + q * 8];
    __syncthreads();
    *(short8*)&As[row * 40 + q * 8] = av;
    *(short8*)&Bs[row * 40 + q * 8] = bv;
    __syncthreads();
    short8 af = *(const short8*)&As[(w4 * 16 + (lane & 15)) * 40 + (lane >> 4) * 8];
    #pragma unroll
    for (int c = 0; c < 4; ++c) {
      short8 bf = *(const short8*)&Bs[(c * 16 + (lane & 15)) * 40 + (lane >> 4) * 8];
      acc[c] = __builtin_amdgcn_mfma_f32_16x16x32_bf16(af, bf, acc[c], 0, 0, 0);
    }
  }
  #pragma unroll
  for (int c = 0; c < 4; ++c) {
    int j = n0 + c * 16 + (lane & 15);
    float bv = bias[j];
    #pragma unroll
    for (int r = 0; r < 4; ++r) {
      int m = m0 + w4 * 16 + (lane >> 4) * 4 + r;
      out[(size_t)m * HIDDEN + j] = acc[c][r] + bv;
    }
  }
}

// ---------------- persistent recurrent kernel ------------------------------
// A-operand: 32 coherent global_load_dwordx4 into VGPRs, counted vmcnt.
// Sync: single counter; tid0 polls one LLC line; fetch_add per WG.
__global__ __launch_bounds__(256) void gru_persist(
    const ushort_t* __restrict__ Wzh, const ushort_t* __restrict__ Whh,
    float* __restrict__ H, float* __restrict__ Z, float* __restrict__ R,
    u64* __restrict__ h_buf, u64* __restrict__ ghb, int* __restrict__ ctr)
{
  extern __shared__ ushort_t smem[];   // [0,32768) Wz, [32768,65536) Wh, [STW,..) scr
  const int w = blockIdx.x;
  const int tid = threadIdx.x;
  const int lane = tid & 63, wv = tid >> 6;
  const int jbase = w * NC;
  const int li = lane & 15, q4 = lane >> 4;
  const int R0 = wv * 16;
  const ushort_t* hgu = (const ushort_t*)h_buf;
  const ushort_t* ggu = (const ushort_t*)ghb;

  // stage weight slices (row-XOR swizzle k ^= (row&7)<<3 for conflict-free B reads)
  for (int c = tid; c < NC * 128; c += 256) {
    int row = c >> 7, k8 = (c & 127) * 8;
    int dst = row * 1024 + (k8 ^ ((row & 7) << 3));
    *(short8*)&smem[dst]         = *(const short8*)&Wzh[(size_t)(jbase + row) * 1024 + k8];
    *(short8*)&smem[32768 + dst] = *(const short8*)&Whh[(size_t)(jbase + row) * 1024 + k8];
  }
  __syncthreads();   // weights ready (h0 + ctr zeroed by host memset; kernels stream-ordered)

  // H[0] = 0 (bulk, background)
  { const int srow = tid >> 2, scc = (tid & 3) * 8;
    float4 z4 = {0.f, 0.f, 0.f, 0.f};
    *(float4*)&H[(size_t)srow * 1024 + jbase + scc]     = z4;
    *(float4*)&H[(size_t)srow * 1024 + jbase + scc + 4] = z4; }

  // per-thread constants
  const int wb0 = li * 1024,     wb1 = (16 + li) * 1024;
  const int sz0 = (li & 7) << 3, sz1 = ((16 + li) & 7) << 3;
  const int koff = q4 * 8;
  const int m0 = wv * 16 + q4 * 4;
  const int sb = STW + wv * 640;                 // per-wave scr [16][40] ushort
  const int str0 = lane >> 3, stc = lane & 7;
  const int gi0 = ((R0 + str0) * 1024 + jbase + stc * 4) >> 2;       // u64 idx
  const int gi1 = ((R0 + 8 + str0) * 1024 + jbase + stc * 4) >> 2;
  const int scr0 = sb + str0 * 40 + stc * 4;
  const int scr1 = sb + (8 + str0) * 40 + stc * 4;
  const ushort_t* gAh = hgu + (size_t)(R0 + li) * 1024 + koff;
  const ushort_t* gAg = ggu + (size_t)(R0 + li) * 1024 + koff;

  float hreg[2][4] = {{0.f,0.f,0.f,0.f},{0.f,0.f,0.f,0.f}};
  short8 a[32];

  for (int t = 0; t < T_STEPS; ++t) {
    const size_t zoff = (size_t)t * BH;

    // ---- phase A: z-gate -------------------------------------------------
    float gz[2][4];
    #pragma unroll
    for (int c = 0; c < 2; ++c)
      #pragma unroll
      for (int r = 0; r < 4; ++r)
        gz[c][r] = Z[zoff + (size_t)(m0 + r) * 1024 + jbase + c * 16 + li];

    poll_ctr(ctr, 64 * t);            // all WGs finished h(t) stores

    f32x4 acc0 = {0,0,0,0}, acc1 = {0,0,0,0};
    ISSUE32(gAh);
    MATVEC16(0, acc0, acc1);

    float g[2][4];
    #pragma unroll
    for (int c = 0; c < 2; ++c)
      #pragma unroll
      for (int r = 0; r < 4; ++r) {
        g[c][r] = sigmoid_f((c ? acc1[r] : acc0[r]) + gz[c][r]);
        smem[sb + (q4 * 4 + r) * 40 + c * 16 + li] = f2bf(g[c][r] * hreg[c][r]);
      }
    asm volatile("s_waitcnt lgkmcnt(0)" ::: "memory");
    __builtin_amdgcn_sched_barrier(0);
    { u64 v0 = *(const u64*)&smem[scr0];
      u64 v1 = *(const u64*)&smem[scr1];
      __hip_atomic_store(ghb + gi0, v0, __ATOMIC_RELAXED, __HIP_MEMORY_SCOPE_AGENT);
      __hip_atomic_store(ghb + gi1, v1, __ATOMIC_RELAXED, __HIP_MEMORY_SCOPE_AGENT); }
    WAITV(0);                          // g*h stores acked at LLC
    __syncthreads();
    if (tid == 0) __hip_atomic_fetch_add(ctr, 1, __ATOMIC_RELAXED, __HIP_MEMORY_SCOPE_AGENT);

    // ---- phase B: candidate ---------------------------------------------
    float gh[2][4];
    #pragma unroll
    for (int c = 0; c < 2; ++c)
      #pragma unroll
      for (int r = 0; r < 4; ++r)
        gh[c][r] = R[zoff + (size_t)(m0 + r) * 1024 + jbase + c * 16 + li];

    poll_ctr(ctr, 64 * t + 32);       // all WGs finished g*h stores

    f32x4 acc2 = {0,0,0,0}, acc3 = {0,0,0,0};
    ISSUE32(gAg);
    MATVEC16(32768, acc2, acc3);

    float hn[2][4];
    #pragma unroll
    for (int c = 0; c < 2; ++c)
      #pragma unroll
      for (int r = 0; r < 4; ++r) {
        float cand = tanh_f((c ? acc3[r] : acc2[r]) + gh[c][r]);
        float v = (1.f - g[c][r]) * hreg[c][r] + g[c][r] * cand;
        hreg[c][r] = v;
        hn[c][r] = v;
        smem[sb + (q4 * 4 + r) * 40 + c * 16 + li] = f2bf(v);
      }
    asm volatile("s_waitcnt lgkmcnt(0)" ::: "memory");
    __builtin_amdgcn_sched_barrier(0);
    { u64 v0 = *(const u64*)&smem[scr0];
      u64 v1 = *(const u64*)&smem[scr1];
      __hip_atomic_store(h_buf + gi0, v0, __ATOMIC_RELAXED, __HIP_MEMORY_SCOPE_AGENT);
      __hip_atomic_store(h_buf + gi1, v1, __ATOMIC_RELAXED, __HIP_MEMORY_SCOPE_AGENT); }
    WAITV(0);                          // h stores acked at LLC
    __syncthreads();
    if (tid == 0) __hip_atomic_fetch_add(ctr, 1, __ATOMIC_RELAXED, __HIP_MEMORY_SCOPE_AGENT);

    // bulk outputs (plain stores, drain in background during next poll)
    const size_t hoff = (size_t)(t + 1) * BH;
    #pragma unroll
    for (int c = 0; c < 2; ++c)
      #pragma unroll
      for (int r = 0; r < 4; ++r) {
        const size_t rowo = (size_t)(m0 + r) * 1024 + jbase + c * 16 + li;
        Z[zoff + rowo] = g[c][r];
        R[zoff + rowo] = g[c][r];
        H[hoff + rowo] = hn[c][r];
      }
  }
}

// ---------------- host launcher -------------------------------------------
extern "C" void kernel_launch(void* const* d_in, const int* in_sizes, int n_in,
                              void* d_out, int out_size, void* d_ws, size_t ws_size,
                              hipStream_t stream) {
  (void)in_sizes; (void)n_in; (void)out_size; (void)ws_size;
  const float* x  = (const float*)d_in[0];
  const float* Wz = (const float*)d_in[1];
  const float* bz = (const float*)d_in[2];
  const float* Wh = (const float*)d_in[3];
  const float* bh = (const float*)d_in[4];

  float* H = (float*)d_out;
  float* Z = H + (size_t)(T_STEPS + 1) * BH;
  float* R = Z + (size_t)T_STEPS * BH;

  char* ws = (char*)d_ws;
  int*      ctr   = (int*)ws;                                   // 16 KB region
  u64*      h_buf = (u64*)(ws + 16384);                         // 128 KB linear bf16
  u64*      ghb   = (u64*)(ws + 16384 + 131072);                // 128 KB linear bf16
  ushort_t* Wzh   = (ushort_t*)(ws + 16384 + 2 * 131072);       // 2 MB
  ushort_t* Whh   = Wzh + (size_t)HIDDEN * HIDDEN;              // 2 MB
  ushort_t* Wzx   = Whh + (size_t)HIDDEN * HIDDEN;              // 1 MB
  ushort_t* Whx   = Wzx + (size_t)HIDDEN * IDIM;                // 1 MB

  hipFuncSetAttribute((const void*)gru_persist,
                      hipFuncAttributeMaxDynamicSharedMemorySize, 136192);

  hipMemsetAsync(ctr, 0, 16384, stream);
  hipMemsetAsync(h_buf, 0, 131072, stream);   // h0 = 0 (kernel-boundary visible)
  convert_weights<<<dim3(HIDDEN, 2), 256, 0, stream>>>(Wz, Wh, Wzh, Wzx, Whh, Whx);
  gx_gemm<<<dim3(T_STEPS * BATCH / 64, HIDDEN / 64, 2), 256, 0, stream>>>(
      x, Wzx, Whx, bz, bh, Z, R);
  gru_persist<<<NWGP, 256, 136192, stream>>>(Wzh, Whh, H, Z, R, h_buf, ghb, ctr);
}

// Round 9
// 6119.072 us; speedup vs baseline: 1.1666x; 1.0136x over previous
//
#include <hip/hip_runtime.h>
#include <cstdint>

typedef unsigned short ushort_t;
typedef __attribute__((ext_vector_type(8))) short short8;
typedef __attribute__((ext_vector_type(4))) float f32x4;
typedef unsigned long long u64;

#define T_STEPS 512
#define BATCH   64
#define IDIM    512
#define HIDDEN  1024
#define NWGP    32          // persistent workgroups
#define NC      32          // output columns per WG
#define BH      (BATCH*HIDDEN)   // 65536
#define STW     65536       // ushort index where per-wave scr begins

__device__ __forceinline__ ushort_t f2bf(float f) {
  unsigned int x = __float_as_uint(f);
  unsigned int r = (x + 0x7fffu + ((x >> 16) & 1u)) >> 16;
  return (ushort_t)r;
}
__device__ __forceinline__ float sigmoid_f(float x) { return 1.f / (1.f + __expf(-x)); }
__device__ __forceinline__ float tanh_f(float x)    { return 1.f - 2.f / (1.f + __expf(2.f * x)); }

// ---- coherent register load: bypass L1+L2, read at LLC ----
#define ALOAD(D, P, OFF) \
  asm volatile("global_load_dwordx4 %0, %1, off offset:" #OFF " sc0 sc1" \
               : "=v"(D) : "v"(P) : "memory")
#define WAITV(N) asm volatile("s_waitcnt vmcnt(" #N ")" ::: "memory")

#define ISSUE32(P) do { \
  ALOAD(a[0],P,0);     ALOAD(a[1],P,64);    ALOAD(a[2],P,128);   ALOAD(a[3],P,192);  \
  ALOAD(a[4],P,256);   ALOAD(a[5],P,320);   ALOAD(a[6],P,384);   ALOAD(a[7],P,448);  \
  ALOAD(a[8],P,512);   ALOAD(a[9],P,576);   ALOAD(a[10],P,640);  ALOAD(a[11],P,704); \
  ALOAD(a[12],P,768);  ALOAD(a[13],P,832);  ALOAD(a[14],P,896);  ALOAD(a[15],P,960); \
  ALOAD(a[16],P,1024); ALOAD(a[17],P,1088); ALOAD(a[18],P,1152); ALOAD(a[19],P,1216);\
  ALOAD(a[20],P,1280); ALOAD(a[21],P,1344); ALOAD(a[22],P,1408); ALOAD(a[23],P,1472);\
  ALOAD(a[24],P,1536); ALOAD(a[25],P,1600); ALOAD(a[26],P,1664); ALOAD(a[27],P,1728);\
  ALOAD(a[28],P,1792); ALOAD(a[29],P,1856); ALOAD(a[30],P,1920); ALOAD(a[31],P,1984);\
} while (0)

// B ds_reads issue BEFORE the vmcnt wait (overlap LDS reads with LLC latency)
#define KSTEP(J, VN, WOFF, A0, A1) do { \
  const int k0_ = (J) * 64 + koff; \
  short8 b00_ = *(const short8*)&smem[(WOFF) + wb0 + (k0_ ^ sz0)]; \
  short8 b10_ = *(const short8*)&smem[(WOFF) + wb1 + (k0_ ^ sz1)]; \
  short8 b01_ = *(const short8*)&smem[(WOFF) + wb0 + ((k0_ + 32) ^ sz0)]; \
  short8 b11_ = *(const short8*)&smem[(WOFF) + wb1 + ((k0_ + 32) ^ sz1)]; \
  WAITV(VN); \
  __builtin_amdgcn_sched_barrier(0); \
  A0 = __builtin_amdgcn_mfma_f32_16x16x32_bf16(a[2*(J)],   b00_, A0, 0, 0, 0); \
  A1 = __builtin_amdgcn_mfma_f32_16x16x32_bf16(a[2*(J)],   b10_, A1, 0, 0, 0); \
  A0 = __builtin_amdgcn_mfma_f32_16x16x32_bf16(a[2*(J)+1], b01_, A0, 0, 0, 0); \
  A1 = __builtin_amdgcn_mfma_f32_16x16x32_bf16(a[2*(J)+1], b11_, A1, 0, 0, 0); \
} while (0)

#define MATVEC16(WOFF, A0, A1) do { \
  KSTEP(0,30,WOFF,A0,A1);  KSTEP(1,28,WOFF,A0,A1);  KSTEP(2,26,WOFF,A0,A1);  KSTEP(3,24,WOFF,A0,A1); \
  KSTEP(4,22,WOFF,A0,A1);  KSTEP(5,20,WOFF,A0,A1);  KSTEP(6,18,WOFF,A0,A1);  KSTEP(7,16,WOFF,A0,A1); \
  KSTEP(8,14,WOFF,A0,A1);  KSTEP(9,12,WOFF,A0,A1);  KSTEP(10,10,WOFF,A0,A1); KSTEP(11,8,WOFF,A0,A1); \
  KSTEP(12,6,WOFF,A0,A1);  KSTEP(13,4,WOFF,A0,A1);  KSTEP(14,2,WOFF,A0,A1);  KSTEP(15,0,WOFF,A0,A1); \
} while (0)

// flag-array barrier: wave 0 gathers all 32 per-WG flags in ONE vector load
// (32 parallel LLC line reads, no RMW), __all ballot, syncthreads broadcast.
// Then WAITV(0): poll loads + every wave's stale ops are drained so the
// counted vmcnt ladder in MATVEC16 is exact for ALL waves.
#define POLL_FLAGS(TGT) do { \
  if (tid < 64) { \
    const int* fp_ = flags + (lane & 31) * 32; \
    for (;;) { \
      int v_; \
      asm volatile("global_load_dword %0, %1, off sc0 sc1\n\ts_waitcnt vmcnt(0)" \
                   : "=v"(v_) : "v"(fp_) : "memory"); \
      if (__all(v_ >= (TGT))) break; \
      __builtin_amdgcn_s_sleep(1); \
    } \
  } \
  __syncthreads(); \
  WAITV(0); \
  __builtin_amdgcn_sched_barrier(0); \
} while (0)

// ---------------- weight conversion: f32 -> bf16, split h-part / x-part ----
__global__ __launch_bounds__(256) void convert_weights(
    const float* __restrict__ Wz, const float* __restrict__ Wh,
    ushort_t* __restrict__ Wzh, ushort_t* __restrict__ Wzx,
    ushort_t* __restrict__ Whh, ushort_t* __restrict__ Whx)
{
  int j = blockIdx.x;
  const float* W = blockIdx.y ? Wh : Wz;
  ushort_t* Bh = blockIdx.y ? Whh : Wzh;
  ushort_t* Bx = blockIdx.y ? Whx : Wzx;
  const float* row = W + (size_t)j * (HIDDEN + IDIM);
  for (int c = threadIdx.x; c < HIDDEN + IDIM; c += 256) {
    ushort_t v = f2bf(row[c]);
    if (c < HIDDEN) Bh[(size_t)j * HIDDEN + c] = v;
    else            Bx[(size_t)j * IDIM + (c - HIDDEN)] = v;
  }
}

// ---------------- phase 1: Gx = x @ Wx^T + b  (two GEMMs via blockIdx.z) ----
__global__ __launch_bounds__(256) void gx_gemm(
    const float* __restrict__ x,
    const ushort_t* __restrict__ Wzx, const ushort_t* __restrict__ Whx,
    const float* __restrict__ bz, const float* __restrict__ bh,
    float* __restrict__ outZ, float* __restrict__ outR)
{
  const int which = blockIdx.z;
  const ushort_t* W = which ? Whx : Wzx;
  const float* bias = which ? bh : bz;
  float* out = which ? outR : outZ;
  const int m0 = blockIdx.x * 64;
  const int n0 = blockIdx.y * 64;
  __shared__ ushort_t As[64 * 40];
  __shared__ ushort_t Bs[64 * 40];
  const int tid = threadIdx.x;
  const int lane = tid & 63, w4 = tid >> 6;
  const int row = tid >> 2, q = tid & 3;
  f32x4 acc[4] = {{0,0,0,0},{0,0,0,0},{0,0,0,0},{0,0,0,0}};
  for (int kk = 0; kk < IDIM; kk += 32) {
    const float* xs = &x[(size_t)(m0 + row) * IDIM + kk + q * 8];
    float4 f0 = *(const float4*)xs;
    float4 f1 = *(const float4*)(xs + 4);
    short8 av;
    av[0]=f2bf(f0.x); av[1]=f2bf(f0.y); av[2]=f2bf(f0.z); av[3]=f2bf(f0.w);
    av[4]=f2bf(f1.x); av[5]=f2bf(f1.y); av[6]=f2bf(f1.z); av[7]=f2bf(f1.w);
    short8 bv = *(const short8*)&W[(size_t)(n0 + row) * IDIM + kk + q * 8];
    __syncthreads();
    *(short8*)&As[row * 40 + q * 8] = av;
    *(short8*)&Bs[row * 40 + q * 8] = bv;
    __syncthreads();
    short8 af = *(const short8*)&As[(w4 * 16 + (lane & 15)) * 40 + (lane >> 4) * 8];
    #pragma unroll
    for (int c = 0; c < 4; ++c) {
      short8 bf = *(const short8*)&Bs[(c * 16 + (lane & 15)) * 40 + (lane >> 4) * 8];
      acc[c] = __builtin_amdgcn_mfma_f32_16x16x32_bf16(af, bf, acc[c], 0, 0, 0);
    }
  }
  #pragma unroll
  for (int c = 0; c < 4; ++c) {
    int j = n0 + c * 16 + (lane & 15);
    float bv = bias[j];
    #pragma unroll
    for (int r = 0; r < 4; ++r) {
      int m = m0 + w4 * 16 + (lane >> 4) * 4 + r;
      out[(size_t)m * HIDDEN + j] = acc[c][r] + bv;
    }
  }
}

// ---------------- persistent recurrent kernel ------------------------------
// A-operand: 32 coherent global_load_dwordx4 into VGPRs, counted vmcnt.
// Sync: per-WG flag lines (plain sc1 store arrival — no RMW serialization);
// wave-0 vector-gather detect.
__global__ __launch_bounds__(256) void gru_persist(
    const ushort_t* __restrict__ Wzh, const ushort_t* __restrict__ Whh,
    float* __restrict__ H, float* __restrict__ Z, float* __restrict__ R,
    u64* __restrict__ h_buf, u64* __restrict__ ghb, int* __restrict__ flags)
{
  extern __shared__ ushort_t smem[];   // [0,32768) Wz, [32768,65536) Wh, [STW,..) scr
  const int w = blockIdx.x;
  const int tid = threadIdx.x;
  const int lane = tid & 63, wv = tid >> 6;
  const int jbase = w * NC;
  const int li = lane & 15, q4 = lane >> 4;
  const int R0 = wv * 16;
  const ushort_t* hgu = (const ushort_t*)h_buf;
  const ushort_t* ggu = (const ushort_t*)ghb;

  // stage weight slices (row-XOR swizzle k ^= (row&7)<<3 for conflict-free B reads)
  for (int c = tid; c < NC * 128; c += 256) {
    int row = c >> 7, k8 = (c & 127) * 8;
    int dst = row * 1024 + (k8 ^ ((row & 7) << 3));
    *(short8*)&smem[dst]         = *(const short8*)&Wzh[(size_t)(jbase + row) * 1024 + k8];
    *(short8*)&smem[32768 + dst] = *(const short8*)&Whh[(size_t)(jbase + row) * 1024 + k8];
  }
  __syncthreads();   // weights ready (h0 + flags zeroed by host memset; stream-ordered)

  // H[0] = 0 (bulk, background)
  { const int srow = tid >> 2, scc = (tid & 3) * 8;
    float4 z4 = {0.f, 0.f, 0.f, 0.f};
    *(float4*)&H[(size_t)srow * 1024 + jbase + scc]     = z4;
    *(float4*)&H[(size_t)srow * 1024 + jbase + scc + 4] = z4; }

  // per-thread constants
  const int wb0 = li * 1024,     wb1 = (16 + li) * 1024;
  const int sz0 = (li & 7) << 3, sz1 = ((16 + li) & 7) << 3;
  const int koff = q4 * 8;
  const int m0 = wv * 16 + q4 * 4;
  const int sb = STW + wv * 640;                 // per-wave scr [16][40] ushort
  const int str0 = lane >> 3, stc = lane & 7;
  const int gi0 = ((R0 + str0) * 1024 + jbase + stc * 4) >> 2;       // u64 idx
  const int gi1 = ((R0 + 8 + str0) * 1024 + jbase + stc * 4) >> 2;
  const int scr0 = sb + str0 * 40 + stc * 4;
  const int scr1 = sb + (8 + str0) * 40 + stc * 4;
  const ushort_t* gAh = hgu + (size_t)(R0 + li) * 1024 + koff;
  const ushort_t* gAg = ggu + (size_t)(R0 + li) * 1024 + koff;
  int* myflag = flags + w * 32;                  // 128B-spaced per-WG flag lines

  float hreg[2][4] = {{0.f,0.f,0.f,0.f},{0.f,0.f,0.f,0.f}};
  short8 a[32];

  for (int t = 0; t < T_STEPS; ++t) {
    const size_t zoff = (size_t)t * BH;

    // ---- phase A: z-gate -------------------------------------------------
    float gz[2][4];
    #pragma unroll
    for (int c = 0; c < 2; ++c)
      #pragma unroll
      for (int r = 0; r < 4; ++r)
        gz[c][r] = Z[zoff + (size_t)(m0 + r) * 1024 + jbase + c * 16 + li];

    POLL_FLAGS(2 * t);                // all WGs finished h(t) stores

    f32x4 acc0 = {0,0,0,0}, acc1 = {0,0,0,0};
    ISSUE32(gAh);
    MATVEC16(0, acc0, acc1);

    float g[2][4];
    #pragma unroll
    for (int c = 0; c < 2; ++c)
      #pragma unroll
      for (int r = 0; r < 4; ++r) {
        g[c][r] = sigmoid_f((c ? acc1[r] : acc0[r]) + gz[c][r]);
        smem[sb + (q4 * 4 + r) * 40 + c * 16 + li] = f2bf(g[c][r] * hreg[c][r]);
      }
    asm volatile("s_waitcnt lgkmcnt(0)" ::: "memory");
    __builtin_amdgcn_sched_barrier(0);
    { u64 v0 = *(const u64*)&smem[scr0];
      u64 v1 = *(const u64*)&smem[scr1];
      __hip_atomic_store(ghb + gi0, v0, __ATOMIC_RELAXED, __HIP_MEMORY_SCOPE_AGENT);
      __hip_atomic_store(ghb + gi1, v1, __ATOMIC_RELAXED, __HIP_MEMORY_SCOPE_AGENT); }
    WAITV(0);                          // g*h stores acked at LLC
    __syncthreads();                   // all waves' stores acked
    if (tid == 0)
      __hip_atomic_store(myflag, 2 * t + 1, __ATOMIC_RELAXED, __HIP_MEMORY_SCOPE_AGENT);

    // ---- phase B: candidate ---------------------------------------------
    float gh[2][4];
    #pragma unroll
    for (int c = 0; c < 2; ++c)
      #pragma unroll
      for (int r = 0; r < 4; ++r)
        gh[c][r] = R[zoff + (size_t)(m0 + r) * 1024 + jbase + c * 16 + li];

    POLL_FLAGS(2 * t + 1);            // all WGs finished g*h stores

    f32x4 acc2 = {0,0,0,0}, acc3 = {0,0,0,0};
    ISSUE32(gAg);
    MATVEC16(32768, acc2, acc3);

    float hn[2][4];
    #pragma unroll
    for (int c = 0; c < 2; ++c)
      #pragma unroll
      for (int r = 0; r < 4; ++r) {
        float cand = tanh_f((c ? acc3[r] : acc2[r]) + gh[c][r]);
        float v = (1.f - g[c][r]) * hreg[c][r] + g[c][r] * cand;
        hreg[c][r] = v;
        hn[c][r] = v;
        smem[sb + (q4 * 4 + r) * 40 + c * 16 + li] = f2bf(v);
      }
    asm volatile("s_waitcnt lgkmcnt(0)" ::: "memory");
    __builtin_amdgcn_sched_barrier(0);
    { u64 v0 = *(const u64*)&smem[scr0];
      u64 v1 = *(const u64*)&smem[scr1];
      __hip_atomic_store(h_buf + gi0, v0, __ATOMIC_RELAXED, __HIP_MEMORY_SCOPE_AGENT);
      __hip_atomic_store(h_buf + gi1, v1, __ATOMIC_RELAXED, __HIP_MEMORY_SCOPE_AGENT); }
    WAITV(0);                          // h stores acked at LLC
    __syncthreads();
    if (tid == 0)
      __hip_atomic_store(myflag, 2 * t + 2, __ATOMIC_RELAXED, __HIP_MEMORY_SCOPE_AGENT);

    // bulk outputs (plain stores, drain in background during next poll)
    const size_t hoff = (size_t)(t + 1) * BH;
    #pragma unroll
    for (int c = 0; c < 2; ++c)
      #pragma unroll
      for (int r = 0; r < 4; ++r) {
        const size_t rowo = (size_t)(m0 + r) * 1024 + jbase + c * 16 + li;
        Z[zoff + rowo] = g[c][r];
        R[zoff + rowo] = g[c][r];
        H[hoff + rowo] = hn[c][r];
      }
  }
}

// ---------------- host launcher -------------------------------------------
extern "C" void kernel_launch(void* const* d_in, const int* in_sizes, int n_in,
                              void* d_out, int out_size, void* d_ws, size_t ws_size,
                              hipStream_t stream) {
  (void)in_sizes; (void)n_in; (void)out_size; (void)ws_size;
  const float* x  = (const float*)d_in[0];
  const float* Wz = (const float*)d_in[1];
  const float* bz = (const float*)d_in[2];
  const float* Wh = (const float*)d_in[3];
  const float* bh = (const float*)d_in[4];

  float* H = (float*)d_out;
  float* Z = H + (size_t)(T_STEPS + 1) * BH;
  float* R = Z + (size_t)T_STEPS * BH;

  char* ws = (char*)d_ws;
  int*      flags = (int*)ws;                                   // 4 KB (32 x 128B)
  u64*      h_buf = (u64*)(ws + 16384);                         // 128 KB linear bf16
  u64*      ghb   = (u64*)(ws + 16384 + 131072);                // 128 KB linear bf16
  ushort_t* Wzh   = (ushort_t*)(ws + 16384 + 2 * 131072);       // 2 MB
  ushort_t* Whh   = Wzh + (size_t)HIDDEN * HIDDEN;              // 2 MB
  ushort_t* Wzx   = Whh + (size_t)HIDDEN * HIDDEN;              // 1 MB
  ushort_t* Whx   = Wzx + (size_t)HIDDEN * IDIM;                // 1 MB

  hipFuncSetAttribute((const void*)gru_persist,
                      hipFuncAttributeMaxDynamicSharedMemorySize, 136192);

  hipMemsetAsync(flags, 0, 16384, stream);
  hipMemsetAsync(h_buf, 0, 131072, stream);   // h0 = 0 (kernel-boundary visible)
  convert_weights<<<dim3(HIDDEN, 2), 256, 0, stream>>>(Wz, Wh, Wzh, Wzx, Whh, Whx);
  gx_gemm<<<dim3(T_STEPS * BATCH / 64, HIDDEN / 64, 2), 256, 0, stream>>>(
      x, Wzx, Whx, bz, bh, Z, R);
  gru_persist<<<NWGP, 256, 136192, stream>>>(Wzh, Whh, H, Z, R, h_buf, ghb, flags);
}

// Round 10
// 4136.479 us; speedup vs baseline: 1.7258x; 1.4793x over previous
//
#include <hip/hip_runtime.h>
#include <cstdint>

typedef unsigned short ushort_t;
typedef __attribute__((ext_vector_type(8))) short short8;
typedef __attribute__((ext_vector_type(4))) float f32x4;
typedef unsigned long long u64;

#define T_STEPS 512
#define BATCH   64
#define IDIM    512
#define HIDDEN  1024
#define NWGP    128         // 4 row-groups x 32 col-slices
#define BH      (BATCH*HIDDEN)   // 65536
// LDS (ushort idx): [0,32768) Wz slice, [32768,65536) Wh slice,
// [65536,66560) SCRR k-reduce (2x64xf32x4), [66560,67200) SCRT [16][40]
#define SCRR    65536
#define SCRT    66560

__device__ __forceinline__ ushort_t f2bf(float f) {
  unsigned int x = __float_as_uint(f);
  unsigned int r = (x + 0x7fffu + ((x >> 16) & 1u)) >> 16;
  return (ushort_t)r;
}
__device__ __forceinline__ float sigmoid_f(float x) { return 1.f / (1.f + __expf(-x)); }
__device__ __forceinline__ float tanh_f(float x)    { return 1.f - 2.f / (1.f + __expf(2.f * x)); }

// ---- coherent register load: bypass L1+L2, read at LLC ----
#define ALOAD(D, P, OFF) \
  asm volatile("global_load_dwordx4 %0, %1, off offset:" #OFF " sc0 sc1" \
               : "=v"(D) : "v"(P) : "memory")
#define WAITV(N) asm volatile("s_waitcnt vmcnt(" #N ")" ::: "memory")

#define ISSUE16(P) do { \
  ALOAD(a[0],P,0);    ALOAD(a[1],P,64);   ALOAD(a[2],P,128);  ALOAD(a[3],P,192);  \
  ALOAD(a[4],P,256);  ALOAD(a[5],P,320);  ALOAD(a[6],P,384);  ALOAD(a[7],P,448);  \
  ALOAD(a[8],P,512);  ALOAD(a[9],P,576);  ALOAD(a[10],P,640); ALOAD(a[11],P,704); \
  ALOAD(a[12],P,768); ALOAD(a[13],P,832); ALOAD(a[14],P,896); ALOAD(a[15],P,960); \
} while (0)

// one col-chain (16 cols), wave's k-half; B ds_read before the vmcnt wait
#define KSTEPF(J, VN, WOFF, A0) do { \
  const int k0_ = kbase + (J) * 32 + koff; \
  short8 b_ = *(const short8*)&smem[(WOFF) + wbF + (k0_ ^ szF)]; \
  WAITV(VN); \
  __builtin_amdgcn_sched_barrier(0); \
  A0 = __builtin_amdgcn_mfma_f32_16x16x32_bf16(a[(J)], b_, A0, 0, 0, 0); \
} while (0)

#define MATVEC16F(WOFF, A0) do { \
  KSTEPF(0,15,WOFF,A0);  KSTEPF(1,14,WOFF,A0);  KSTEPF(2,13,WOFF,A0);  KSTEPF(3,12,WOFF,A0); \
  KSTEPF(4,11,WOFF,A0);  KSTEPF(5,10,WOFF,A0);  KSTEPF(6,9,WOFF,A0);   KSTEPF(7,8,WOFF,A0);  \
  KSTEPF(8,7,WOFF,A0);   KSTEPF(9,6,WOFF,A0);   KSTEPF(10,5,WOFF,A0);  KSTEPF(11,4,WOFF,A0); \
  KSTEPF(12,3,WOFF,A0);  KSTEPF(13,2,WOFF,A0);  KSTEPF(14,1,WOFF,A0);  KSTEPF(15,0,WOFF,A0); \
} while (0)

// per-group barrier (32 WGs): tid0 polls group counter, syncthreads broadcast,
// then all waves drain stale VMEM so the counted vmcnt ladder is exact.
#define POLL_GRP(TGT) do { \
  if (tid == 0) { \
    while (__hip_atomic_load(gctr, __ATOMIC_RELAXED, __HIP_MEMORY_SCOPE_AGENT) < (TGT)) \
      __builtin_amdgcn_s_sleep(1); \
  } \
  __syncthreads(); \
  WAITV(0); \
  __builtin_amdgcn_sched_barrier(0); \
} while (0)

// ---------------- weight conversion: f32 -> bf16, split h-part / x-part ----
__global__ __launch_bounds__(256) void convert_weights(
    const float* __restrict__ Wz, const float* __restrict__ Wh,
    ushort_t* __restrict__ Wzh, ushort_t* __restrict__ Wzx,
    ushort_t* __restrict__ Whh, ushort_t* __restrict__ Whx)
{
  int j = blockIdx.x;
  const float* W = blockIdx.y ? Wh : Wz;
  ushort_t* Bh = blockIdx.y ? Whh : Wzh;
  ushort_t* Bx = blockIdx.y ? Whx : Wzx;
  const float* row = W + (size_t)j * (HIDDEN + IDIM);
  for (int c = threadIdx.x; c < HIDDEN + IDIM; c += 256) {
    ushort_t v = f2bf(row[c]);
    if (c < HIDDEN) Bh[(size_t)j * HIDDEN + c] = v;
    else            Bx[(size_t)j * IDIM + (c - HIDDEN)] = v;
  }
}

// ---------------- phase 1: Gx = x @ Wx^T + b  (two GEMMs via blockIdx.z) ----
__global__ __launch_bounds__(256) void gx_gemm(
    const float* __restrict__ x,
    const ushort_t* __restrict__ Wzx, const ushort_t* __restrict__ Whx,
    const float* __restrict__ bz, const float* __restrict__ bh,
    float* __restrict__ outZ, float* __restrict__ outR)
{
  const int which = blockIdx.z;
  const ushort_t* W = which ? Whx : Wzx;
  const float* bias = which ? bh : bz;
  float* out = which ? outR : outZ;
  const int m0 = blockIdx.x * 64;
  const int n0 = blockIdx.y * 64;
  __shared__ ushort_t As[64 * 40];
  __shared__ ushort_t Bs[64 * 40];
  const int tid = threadIdx.x;
  const int lane = tid & 63, w4 = tid >> 6;
  const int row = tid >> 2, q = tid & 3;
  f32x4 acc[4] = {{0,0,0,0},{0,0,0,0},{0,0,0,0},{0,0,0,0}};
  for (int kk = 0; kk < IDIM; kk += 32) {
    const float* xs = &x[(size_t)(m0 + row) * IDIM + kk + q * 8];
    float4 f0 = *(const float4*)xs;
    float4 f1 = *(const float4*)(xs + 4);
    short8 av;
    av[0]=f2bf(f0.x); av[1]=f2bf(f0.y); av[2]=f2bf(f0.z); av[3]=f2bf(f0.w);
    av[4]=f2bf(f1.x); av[5]=f2bf(f1.y); av[6]=f2bf(f1.z); av[7]=f2bf(f1.w);
    short8 bv = *(const short8*)&W[(size_t)(n0 + row) * IDIM + kk + q * 8];
    __syncthreads();
    *(short8*)&As[row * 40 + q * 8] = av;
    *(short8*)&Bs[row * 40 + q * 8] = bv;
    __syncthreads();
    short8 af = *(const short8*)&As[(w4 * 16 + (lane & 15)) * 40 + (lane >> 4) * 8];
    #pragma unroll
    for (int c = 0; c < 4; ++c) {
      short8 bf = *(const short8*)&Bs[(c * 16 + (lane & 15)) * 40 + (lane >> 4) * 8];
      acc[c] = __builtin_amdgcn_mfma_f32_16x16x32_bf16(af, bf, acc[c], 0, 0, 0);
    }
  }
  #pragma unroll
  for (int c = 0; c < 4; ++c) {
    int j = n0 + c * 16 + (lane & 15);
    float bv = bias[j];
    #pragma unroll
    for (int r = 0; r < 4; ++r) {
      int m = m0 + w4 * 16 + (lane >> 4) * 4 + r;
      out[(size_t)m * HIDDEN + j] = acc[c][r] + bv;
    }
  }
}

// ---------------- persistent recurrent kernel ------------------------------
// 4 independent row-groups (16 batch rows each) x 32 col-slice WGs.
// Per WG: 16 rows x 32 cols. Per wave: 16 cols x K/2, 16 coherent loads,
// counted vmcnt, 2-way k-reduce via LDS. Sync: per-group 32-WG counter.
__global__ __launch_bounds__(256) void gru_persist(
    const ushort_t* __restrict__ Wzh, const ushort_t* __restrict__ Whh,
    float* __restrict__ H, float* __restrict__ Z, float* __restrict__ R,
    u64* __restrict__ h_buf, u64* __restrict__ ghb, int* __restrict__ ctrs)
{
  extern __shared__ ushort_t smem[];
  const int tid = threadIdx.x;
  const int lane = tid & 63, wv = tid >> 6;
  const int grp = blockIdx.x >> 5, slot = blockIdx.x & 31;
  const int rbase = grp * 16;            // batch-row block
  const int jbase = slot * 32;           // output-column block
  int* gctr = ctrs + grp * 32;           // 128B-spaced group counters
  const ushort_t* hgu = (const ushort_t*)h_buf;
  const ushort_t* ggu = (const ushort_t*)ghb;

  // stage weight slices (row-XOR swizzle k ^= (row&7)<<3)
  for (int c = tid; c < 32 * 128; c += 256) {
    int row = c >> 7, k8 = (c & 127) * 8;
    int dst = row * 1024 + (k8 ^ ((row & 7) << 3));
    *(short8*)&smem[dst]         = *(const short8*)&Wzh[(size_t)(jbase + row) * 1024 + k8];
    *(short8*)&smem[32768 + dst] = *(const short8*)&Whh[(size_t)(jbase + row) * 1024 + k8];
  }
  __syncthreads();   // weights ready (h0 + ctrs zeroed by host memset)

  // H[0] = 0 for this WG's 16x32 block (background)
  if (tid < 128) {
    const int row = tid >> 3, ch = tid & 7;
    float4 z4 = {0.f, 0.f, 0.f, 0.f};
    *(float4*)&H[(size_t)(rbase + row) * 1024 + jbase + ch * 4] = z4;
  }

  // wave decomposition: wc = col sub-block, kh = k-half
  const int li = lane & 15, q4 = lane >> 4;
  const int wc = (wv & 1) * 16;
  const int kh = wv >> 1;
  const int kbase = kh * 512;
  const int koff = q4 * 8;
  const int wbF = (wc + li) * 1024;
  const int szF = ((wc + li) & 7) << 3;
  const int m0 = q4 * 4;                 // epilogue rows (kh==0 waves)
  const int col = jbase + wc + li;       // epilogue column
  // A-operand pointers: row = rbase + li, k-half start
  const ushort_t* pAh = hgu + (size_t)(rbase + li) * 1024 + kbase + koff;
  const ushort_t* pAg = ggu + (size_t)(rbase + li) * 1024 + kbase + koff;
  // broadcast-store mapping (tid<128): row = tid>>3, 4-col chunk tid&7
  const int brow = tid >> 3, bch = tid & 7;
  const int bidx = (rbase + brow) * 256 + (jbase >> 2) + bch;   // u64 idx
  const int scrt_rd = SCRT + brow * 40 + bch * 4;
  // SCRR slot for k-reduction (per col-block, per lane)
  const int rr = SCRR + ((wv & 1) * 64 + lane) * 8;

  float hreg[4] = {0.f, 0.f, 0.f, 0.f};
  float g[4], hn[4];
  short8 a[16];

  for (int t = 0; t < T_STEPS; ++t) {
    const size_t zoff = (size_t)t * BH;

    // ---- phase A: z-gate -------------------------------------------------
    float gz[4];
    if (kh == 0)
      #pragma unroll
      for (int r = 0; r < 4; ++r)
        gz[r] = Z[zoff + (size_t)(rbase + m0 + r) * 1024 + col];

    POLL_GRP(64 * t);                 // group finished h(t) stores

    f32x4 acc = {0, 0, 0, 0};
    ISSUE16(pAh);
    MATVEC16F(0, acc);

    // 2-way k-reduction across wave pairs
    if (kh) *(f32x4*)&smem[rr] = acc;
    __syncthreads();
    if (kh == 0) {
      f32x4 o = *(const f32x4*)&smem[rr];
      #pragma unroll
      for (int r = 0; r < 4; ++r) {
        g[r] = sigmoid_f(acc[r] + o[r] + gz[r]);
        smem[SCRT + (m0 + r) * 40 + wc + li] = f2bf(g[r] * hreg[r]);
      }
    }
    __syncthreads();
    if (tid < 128) {
      u64 v = *(const u64*)&smem[scrt_rd];
      __hip_atomic_store(ghb + bidx, v, __ATOMIC_RELAXED, __HIP_MEMORY_SCOPE_AGENT);
    }
    WAITV(0);                          // g*h stores acked at LLC
    __syncthreads();
    if (tid == 0)
      __hip_atomic_fetch_add(gctr, 1, __ATOMIC_RELAXED, __HIP_MEMORY_SCOPE_AGENT);

    // ---- phase B: candidate ---------------------------------------------
    float gh[4];
    if (kh == 0)
      #pragma unroll
      for (int r = 0; r < 4; ++r)
        gh[r] = R[zoff + (size_t)(rbase + m0 + r) * 1024 + col];

    POLL_GRP(64 * t + 32);            // group finished g*h stores

    f32x4 acc2 = {0, 0, 0, 0};
    ISSUE16(pAg);
    MATVEC16F(32768, acc2);

    if (kh) *(f32x4*)&smem[rr] = acc2;
    __syncthreads();
    if (kh == 0) {
      f32x4 o = *(const f32x4*)&smem[rr];
      #pragma unroll
      for (int r = 0; r < 4; ++r) {
        float cand = tanh_f(acc2[r] + o[r] + gh[r]);
        hn[r] = (1.f - g[r]) * hreg[r] + g[r] * cand;
        hreg[r] = hn[r];
        smem[SCRT + (m0 + r) * 40 + wc + li] = f2bf(hn[r]);
      }
    }
    __syncthreads();
    if (tid < 128) {
      u64 v = *(const u64*)&smem[scrt_rd];
      __hip_atomic_store(h_buf + bidx, v, __ATOMIC_RELAXED, __HIP_MEMORY_SCOPE_AGENT);
    }
    WAITV(0);                          // h stores acked at LLC
    __syncthreads();
    if (tid == 0)
      __hip_atomic_fetch_add(gctr, 1, __ATOMIC_RELAXED, __HIP_MEMORY_SCOPE_AGENT);

    // bulk outputs (kh==0 waves; drain in background during next poll)
    if (kh == 0) {
      const size_t hoff = (size_t)(t + 1) * BH;
      #pragma unroll
      for (int r = 0; r < 4; ++r) {
        const size_t rowo = (size_t)(rbase + m0 + r) * 1024 + col;
        Z[zoff + rowo] = g[r];
        R[zoff + rowo] = g[r];
        H[hoff + rowo] = hn[r];
      }
    }
  }
}

// ---------------- host launcher -------------------------------------------
extern "C" void kernel_launch(void* const* d_in, const int* in_sizes, int n_in,
                              void* d_out, int out_size, void* d_ws, size_t ws_size,
                              hipStream_t stream) {
  (void)in_sizes; (void)n_in; (void)out_size; (void)ws_size;
  const float* x  = (const float*)d_in[0];
  const float* Wz = (const float*)d_in[1];
  const float* bz = (const float*)d_in[2];
  const float* Wh = (const float*)d_in[3];
  const float* bh = (const float*)d_in[4];

  float* H = (float*)d_out;
  float* Z = H + (size_t)(T_STEPS + 1) * BH;
  float* R = Z + (size_t)T_STEPS * BH;

  char* ws = (char*)d_ws;
  int*      ctrs  = (int*)ws;                                   // 4 group ctrs, 128B apart
  u64*      h_buf = (u64*)(ws + 16384);                         // 128 KB linear bf16
  u64*      ghb   = (u64*)(ws + 16384 + 131072);                // 128 KB linear bf16
  ushort_t* Wzh   = (ushort_t*)(ws + 16384 + 2 * 131072);       // 2 MB
  ushort_t* Whh   = Wzh + (size_t)HIDDEN * HIDDEN;              // 2 MB
  ushort_t* Wzx   = Whh + (size_t)HIDDEN * HIDDEN;              // 1 MB
  ushort_t* Whx   = Wzx + (size_t)HIDDEN * IDIM;                // 1 MB

  hipFuncSetAttribute((const void*)gru_persist,
                      hipFuncAttributeMaxDynamicSharedMemorySize, 134400);

  hipMemsetAsync(ctrs, 0, 16384, stream);
  hipMemsetAsync(h_buf, 0, 131072, stream);   // h0 = 0 (kernel-boundary visible)
  convert_weights<<<dim3(HIDDEN, 2), 256, 0, stream>>>(Wz, Wh, Wzh, Wzx, Whh, Whx);
  gx_gemm<<<dim3(T_STEPS * BATCH / 64, HIDDEN / 64, 2), 256, 0, stream>>>(
      x, Wzx, Whx, bz, bh, Z, R);
  gru_persist<<<NWGP, 256, 134400, stream>>>(Wzh, Whh, H, Z, R, h_buf, ghb, ctrs);
}

// Round 11
// 3447.153 us; speedup vs baseline: 2.0709x; 1.2000x over previous
//
#include <hip/hip_runtime.h>
#include <cstdint>

typedef unsigned short ushort_t;
typedef __attribute__((ext_vector_type(8))) short short8;
typedef __attribute__((ext_vector_type(4))) float f32x4;
typedef unsigned long long u64;

#define T_STEPS 512
#define BATCH   64
#define IDIM    512
#define HIDDEN  1024
#define NWGP    128         // 4 row-groups x 32 col-slices
#define BH      (BATCH*HIDDEN)   // 65536
// LDS (ushort idx): [0,32768) Wz slice, [32768,65536) Wh slice,
// [65536,69632) SCRR k-reduce (2 chains x 4 quarters x 64 lanes x 16B),
// [69632,70272) SCRT [16][40]. Total 70272 ushorts = 140544 B.
#define SCRR    65536
#define SCRT    69632

__device__ __forceinline__ ushort_t f2bf(float f) {
  unsigned int x = __float_as_uint(f);
  unsigned int r = (x + 0x7fffu + ((x >> 16) & 1u)) >> 16;
  return (ushort_t)r;
}
__device__ __forceinline__ float sigmoid_f(float x) { return 1.f / (1.f + __expf(-x)); }
__device__ __forceinline__ float tanh_f(float x)    { return 1.f - 2.f / (1.f + __expf(2.f * x)); }

// ---- coherent register load: bypass L1+L2, read at LLC ----
#define ALOAD(D, P, OFF) \
  asm volatile("global_load_dwordx4 %0, %1, off offset:" #OFF " sc0 sc1" \
               : "=v"(D) : "v"(P) : "memory")
#define WAITV(N) asm volatile("s_waitcnt vmcnt(" #N ")" ::: "memory")

// 8 loads: one k-quarter (256 elems) for 16 rows, 16B/lane each
#define ISSUE8(P) do { \
  ALOAD(a[0],P,0);    ALOAD(a[1],P,64);   ALOAD(a[2],P,128);  ALOAD(a[3],P,192);  \
  ALOAD(a[4],P,256);  ALOAD(a[5],P,320);  ALOAD(a[6],P,384);  ALOAD(a[7],P,448);  \
} while (0)

// dual col-chain K-step: both chains consume the same A quarter
#define KSTEP2(J, VN, WOFF) do { \
  const int k0_ = kqbase + (J) * 32 + koff; \
  short8 b0_ = *(const short8*)&smem[(WOFF) + wb0 + (k0_ ^ sz0)]; \
  short8 b1_ = *(const short8*)&smem[(WOFF) + wb1 + (k0_ ^ sz1)]; \
  WAITV(VN); \
  __builtin_amdgcn_sched_barrier(0); \
  acc0 = __builtin_amdgcn_mfma_f32_16x16x32_bf16(a[(J)], b0_, acc0, 0, 0, 0); \
  acc1 = __builtin_amdgcn_mfma_f32_16x16x32_bf16(a[(J)], b1_, acc1, 0, 0, 0); \
} while (0)

#define MATVEC8(WOFF) do { \
  KSTEP2(0,7,WOFF); KSTEP2(1,6,WOFF); KSTEP2(2,5,WOFF); KSTEP2(3,4,WOFF); \
  KSTEP2(4,3,WOFF); KSTEP2(5,2,WOFF); KSTEP2(6,1,WOFF); KSTEP2(7,0,WOFF); \
} while (0)

// per-group barrier (32 WGs): tid0 polls group counter, syncthreads broadcast,
// then all waves drain stale VMEM so the counted vmcnt ladder is exact.
#define POLL_GRP(TGT) do { \
  if (tid == 0) { \
    while (__hip_atomic_load(gctr, __ATOMIC_RELAXED, __HIP_MEMORY_SCOPE_AGENT) < (TGT)) \
      __builtin_amdgcn_s_sleep(1); \
  } \
  __syncthreads(); \
  WAITV(0); \
  __builtin_amdgcn_sched_barrier(0); \
} while (0)

// ---------------- weight conversion: f32 -> bf16, split h-part / x-part ----
__global__ __launch_bounds__(256) void convert_weights(
    const float* __restrict__ Wz, const float* __restrict__ Wh,
    ushort_t* __restrict__ Wzh, ushort_t* __restrict__ Wzx,
    ushort_t* __restrict__ Whh, ushort_t* __restrict__ Whx)
{
  int j = blockIdx.x;
  const float* W = blockIdx.y ? Wh : Wz;
  ushort_t* Bh = blockIdx.y ? Whh : Wzh;
  ushort_t* Bx = blockIdx.y ? Whx : Wzx;
  const float* row = W + (size_t)j * (HIDDEN + IDIM);
  for (int c = threadIdx.x; c < HIDDEN + IDIM; c += 256) {
    ushort_t v = f2bf(row[c]);
    if (c < HIDDEN) Bh[(size_t)j * HIDDEN + c] = v;
    else            Bx[(size_t)j * IDIM + (c - HIDDEN)] = v;
  }
}

// ---------------- phase 1: Gx = x @ Wx^T + b  (two GEMMs via blockIdx.z) ----
__global__ __launch_bounds__(256) void gx_gemm(
    const float* __restrict__ x,
    const ushort_t* __restrict__ Wzx, const ushort_t* __restrict__ Whx,
    const float* __restrict__ bz, const float* __restrict__ bh,
    float* __restrict__ outZ, float* __restrict__ outR)
{
  const int which = blockIdx.z;
  const ushort_t* W = which ? Whx : Wzx;
  const float* bias = which ? bh : bz;
  float* out = which ? outR : outZ;
  const int m0 = blockIdx.x * 64;
  const int n0 = blockIdx.y * 64;
  __shared__ ushort_t As[64 * 40];
  __shared__ ushort_t Bs[64 * 40];
  const int tid = threadIdx.x;
  const int lane = tid & 63, w4 = tid >> 6;
  const int row = tid >> 2, q = tid & 3;
  f32x4 acc[4] = {{0,0,0,0},{0,0,0,0},{0,0,0,0},{0,0,0,0}};
  for (int kk = 0; kk < IDIM; kk += 32) {
    const float* xs = &x[(size_t)(m0 + row) * IDIM + kk + q * 8];
    float4 f0 = *(const float4*)xs;
    float4 f1 = *(const float4*)(xs + 4);
    short8 av;
    av[0]=f2bf(f0.x); av[1]=f2bf(f0.y); av[2]=f2bf(f0.z); av[3]=f2bf(f0.w);
    av[4]=f2bf(f1.x); av[5]=f2bf(f1.y); av[6]=f2bf(f1.z); av[7]=f2bf(f1.w);
    short8 bv = *(const short8*)&W[(size_t)(n0 + row) * IDIM + kk + q * 8];
    __syncthreads();
    *(short8*)&As[row * 40 + q * 8] = av;
    *(short8*)&Bs[row * 40 + q * 8] = bv;
    __syncthreads();
    short8 af = *(const short8*)&As[(w4 * 16 + (lane & 15)) * 40 + (lane >> 4) * 8];
    #pragma unroll
    for (int c = 0; c < 4; ++c) {
      short8 bf = *(const short8*)&Bs[(c * 16 + (lane & 15)) * 40 + (lane >> 4) * 8];
      acc[c] = __builtin_amdgcn_mfma_f32_16x16x32_bf16(af, bf, acc[c], 0, 0, 0);
    }
  }
  #pragma unroll
  for (int c = 0; c < 4; ++c) {
    int j = n0 + c * 16 + (lane & 15);
    float bv = bias[j];
    #pragma unroll
    for (int r = 0; r < 4; ++r) {
      int m = m0 + w4 * 16 + (lane >> 4) * 4 + r;
      out[(size_t)m * HIDDEN + j] = acc[c][r] + bv;
    }
  }
}

// ---------------- persistent recurrent kernel ------------------------------
// 4 independent row-groups (16 batch rows each) x 32 col-slice WGs.
// Per WG: 16 rows x 32 cols. Per wave: one k-QUARTER (8 coherent loads,
// counted vmcnt), BOTH col-chains from the same A regs (no duplicate loads).
// 4-way k-reduce via LDS; epilogue on waves 0 (cols 0-15) and 1 (cols 16-31).
__global__ __launch_bounds__(256) void gru_persist(
    const ushort_t* __restrict__ Wzh, const ushort_t* __restrict__ Whh,
    float* __restrict__ H, float* __restrict__ Z, float* __restrict__ R,
    u64* __restrict__ h_buf, u64* __restrict__ ghb, int* __restrict__ ctrs)
{
  extern __shared__ ushort_t smem[];
  const int tid = threadIdx.x;
  const int lane = tid & 63, wv = tid >> 6;
  const int grp = blockIdx.x >> 5, slot = blockIdx.x & 31;
  const int rbase = grp * 16;            // batch-row block
  const int jbase = slot * 32;           // output-column block
  int* gctr = ctrs + grp * 32;           // 128B-spaced group counters
  const ushort_t* hgu = (const ushort_t*)h_buf;
  const ushort_t* ggu = (const ushort_t*)ghb;

  // stage weight slices (row-XOR swizzle k ^= (row&7)<<3)
  for (int c = tid; c < 32 * 128; c += 256) {
    int row = c >> 7, k8 = (c & 127) * 8;
    int dst = row * 1024 + (k8 ^ ((row & 7) << 3));
    *(short8*)&smem[dst]         = *(const short8*)&Wzh[(size_t)(jbase + row) * 1024 + k8];
    *(short8*)&smem[32768 + dst] = *(const short8*)&Whh[(size_t)(jbase + row) * 1024 + k8];
  }
  __syncthreads();   // weights ready (h0 + ctrs zeroed by host memset)

  // H[0] = 0 for this WG's 16x32 block (background)
  if (tid < 128) {
    const int row = tid >> 3, ch = tid & 7;
    float4 z4 = {0.f, 0.f, 0.f, 0.f};
    *(float4*)&H[(size_t)(rbase + row) * 1024 + jbase + ch * 4] = z4;
  }

  // wave decomposition: wv = k-quarter; epilogue chains on waves 0,1
  const int li = lane & 15, q4 = lane >> 4;
  const int kqbase = wv * 256;
  const int koff = q4 * 8;
  const int wb0 = li * 1024,     wb1 = (16 + li) * 1024;
  const int sz0 = (li & 7) << 3, sz1 = ((16 + li) & 7) << 3;
  const int m0 = q4 * 4;                 // epilogue rows (waves 0,1)
  const int col = jbase + (wv & 1) * 16 + li;   // epilogue column (waves 0,1)
  // A-operand pointers: row = rbase + li, k-quarter start
  const ushort_t* pAh = hgu + (size_t)(rbase + li) * 1024 + kqbase + koff;
  const ushort_t* pAg = ggu + (size_t)(rbase + li) * 1024 + kqbase + koff;
  // broadcast-store mapping (tid<128): row = tid>>3, 4-col u64 chunk tid&7
  const int brow = tid >> 3, bch = tid & 7;
  const int bidx = (rbase + brow) * 256 + (jbase >> 2) + bch;   // u64 idx
  const int scrt_rd = SCRT + brow * 40 + bch * 4;
  // SCRR slots: [chain][quarter][lane] x 16B
  const int rr0 = SCRR + ((0 * 4 + wv) * 64 + lane) * 8;
  const int rr1 = SCRR + ((1 * 4 + wv) * 64 + lane) * 8;
  const int rrc = SCRR + ((wv & 1) * 4 * 64 + lane) * 8;   // epilogue chain base

  float hreg[4] = {0.f, 0.f, 0.f, 0.f};
  float g[4], hn[4];
  short8 a[8];

  for (int t = 0; t < T_STEPS; ++t) {
    const size_t zoff = (size_t)t * BH;

    // ---- phase A: z-gate -------------------------------------------------
    float gz[4];
    if (wv < 2)
      #pragma unroll
      for (int r = 0; r < 4; ++r)
        gz[r] = Z[zoff + (size_t)(rbase + m0 + r) * 1024 + col];

    POLL_GRP(64 * t);                 // group finished h(t) stores

    f32x4 acc0 = {0, 0, 0, 0}, acc1 = {0, 0, 0, 0};
    ISSUE8(pAh);
    MATVEC8(0);

    // 4-way k-reduction: all waves deposit both chains
    *(f32x4*)&smem[rr0] = acc0;
    *(f32x4*)&smem[rr1] = acc1;
    __syncthreads();
    if (wv < 2) {
      f32x4 s = *(const f32x4*)&smem[rrc];
      #pragma unroll
      for (int q = 1; q < 4; ++q) {
        f32x4 o = *(const f32x4*)&smem[rrc + q * 64 * 8];
        #pragma unroll
        for (int r = 0; r < 4; ++r) s[r] += o[r];
      }
      #pragma unroll
      for (int r = 0; r < 4; ++r) {
        g[r] = sigmoid_f(s[r] + gz[r]);
        smem[SCRT + (m0 + r) * 40 + (wv & 1) * 16 + li] = f2bf(g[r] * hreg[r]);
      }
    }
    __syncthreads();
    if (tid < 128) {
      u64 v = *(const u64*)&smem[scrt_rd];
      __hip_atomic_store(ghb + bidx, v, __ATOMIC_RELAXED, __HIP_MEMORY_SCOPE_AGENT);
    }
    WAITV(0);                          // g*h stores acked at LLC
    __syncthreads();
    if (tid == 0)
      __hip_atomic_fetch_add(gctr, 1, __ATOMIC_RELAXED, __HIP_MEMORY_SCOPE_AGENT);

    // ---- phase B: candidate ---------------------------------------------
    float gh[4];
    if (wv < 2)
      #pragma unroll
      for (int r = 0; r < 4; ++r)
        gh[r] = R[zoff + (size_t)(rbase + m0 + r) * 1024 + col];

    POLL_GRP(64 * t + 32);            // group finished g*h stores

    acc0 = (f32x4){0, 0, 0, 0}; acc1 = (f32x4){0, 0, 0, 0};
    ISSUE8(pAg);
    MATVEC8(32768);

    *(f32x4*)&smem[rr0] = acc0;
    *(f32x4*)&smem[rr1] = acc1;
    __syncthreads();
    if (wv < 2) {
      f32x4 s = *(const f32x4*)&smem[rrc];
      #pragma unroll
      for (int q = 1; q < 4; ++q) {
        f32x4 o = *(const f32x4*)&smem[rrc + q * 64 * 8];
        #pragma unroll
        for (int r = 0; r < 4; ++r) s[r] += o[r];
      }
      #pragma unroll
      for (int r = 0; r < 4; ++r) {
        float cand = tanh_f(s[r] + gh[r]);
        hn[r] = (1.f - g[r]) * hreg[r] + g[r] * cand;
        hreg[r] = hn[r];
        smem[SCRT + (m0 + r) * 40 + (wv & 1) * 16 + li] = f2bf(hn[r]);
      }
    }
    __syncthreads();
    if (tid < 128) {
      u64 v = *(const u64*)&smem[scrt_rd];
      __hip_atomic_store(h_buf + bidx, v, __ATOMIC_RELAXED, __HIP_MEMORY_SCOPE_AGENT);
    }
    WAITV(0);                          // h stores acked at LLC
    __syncthreads();
    if (tid == 0)
      __hip_atomic_fetch_add(gctr, 1, __ATOMIC_RELAXED, __HIP_MEMORY_SCOPE_AGENT);

    // bulk outputs (epilogue waves; drain in background during next poll)
    if (wv < 2) {
      const size_t hoff = (size_t)(t + 1) * BH;
      #pragma unroll
      for (int r = 0; r < 4; ++r) {
        const size_t rowo = (size_t)(rbase + m0 + r) * 1024 + col;
        Z[zoff + rowo] = g[r];
        R[zoff + rowo] = g[r];
        H[hoff + rowo] = hn[r];
      }
    }
  }
}

// ---------------- host launcher -------------------------------------------
extern "C" void kernel_launch(void* const* d_in, const int* in_sizes, int n_in,
                              void* d_out, int out_size, void* d_ws, size_t ws_size,
                              hipStream_t stream) {
  (void)in_sizes; (void)n_in; (void)out_size; (void)ws_size;
  const float* x  = (const float*)d_in[0];
  const float* Wz = (const float*)d_in[1];
  const float* bz = (const float*)d_in[2];
  const float* Wh = (const float*)d_in[3];
  const float* bh = (const float*)d_in[4];

  float* H = (float*)d_out;
  float* Z = H + (size_t)(T_STEPS + 1) * BH;
  float* R = Z + (size_t)T_STEPS * BH;

  char* ws = (char*)d_ws;
  int*      ctrs  = (int*)ws;                                   // 4 group ctrs, 128B apart
  u64*      h_buf = (u64*)(ws + 16384);                         // 128 KB linear bf16
  u64*      ghb   = (u64*)(ws + 16384 + 131072);                // 128 KB linear bf16
  ushort_t* Wzh   = (ushort_t*)(ws + 16384 + 2 * 131072);       // 2 MB
  ushort_t* Whh   = Wzh + (size_t)HIDDEN * HIDDEN;              // 2 MB
  ushort_t* Wzx   = Whh + (size_t)HIDDEN * HIDDEN;              // 1 MB
  ushort_t* Whx   = Wzx + (size_t)HIDDEN * IDIM;                // 1 MB

  hipFuncSetAttribute((const void*)gru_persist,
                      hipFuncAttributeMaxDynamicSharedMemorySize, 140544);

  hipMemsetAsync(ctrs, 0, 16384, stream);
  hipMemsetAsync(h_buf, 0, 131072, stream);   // h0 = 0 (kernel-boundary visible)
  convert_weights<<<dim3(HIDDEN, 2), 256, 0, stream>>>(Wz, Wh, Wzh, Wzx, Whh, Whx);
  gx_gemm<<<dim3(T_STEPS * BATCH / 64, HIDDEN / 64, 2), 256, 0, stream>>>(
      x, Wzx, Whx, bz, bh, Z, R);
  gru_persist<<<NWGP, 256, 140544, stream>>>(Wzh, Whh, H, Z, R, h_buf, ghb, ctrs);
}

// Round 12
// 2401.289 us; speedup vs baseline: 2.9729x; 1.4355x over previous
//
#include <hip/hip_runtime.h>
#include <cstdint>

typedef unsigned short ushort_t;
typedef __attribute__((ext_vector_type(8))) short short8;
typedef __attribute__((ext_vector_type(4))) float f32x4;
typedef unsigned long long u64;

#define T_STEPS 512
#define BATCH   64
#define IDIM    512
#define HIDDEN  1024
#define NWGP    256         // 8 row-groups (bid&7) x 32 col-slices (bid>>3)
#define BH      (BATCH*HIDDEN)   // 65536
// LDS (ushort idx): [0,32768) Wz slice, [32768,65536) Wh slice,
// [65536,73728) STG A-staging (4 waves x 2KB-ushort), [73728,77824) SCRR,
// [77824,78208) SCRT [8][40]+pad. Total 78208 ushorts = 156416 B.
#define STG     65536
#define SCRR    73728
#define SCRT    77824

__device__ __forceinline__ ushort_t f2bf(float f) {
  unsigned int x = __float_as_uint(f);
  unsigned int r = (x + 0x7fffu + ((x >> 16) & 1u)) >> 16;
  return (ushort_t)r;
}
__device__ __forceinline__ float sigmoid_f(float x) { return 1.f / (1.f + __expf(-x)); }
__device__ __forceinline__ float tanh_f(float x)    { return 1.f - 2.f / (1.f + __expf(2.f * x)); }

#define WAITV(N) asm volatile("s_waitcnt vmcnt(" #N ")" ::: "memory")

// coherent global->LDS direct load, 16B/lane, aux=17 (sc0|sc1): bypass L1+L2,
// read at LLC (R4-proven). Dest is wave-uniform base + lane*16 (linear).
__device__ __forceinline__ void glds16(const ushort_t* g, ushort_t* l) {
  __builtin_amdgcn_global_load_lds(
      (const __attribute__((address_space(1))) void*)g,
      (__attribute__((address_space(3))) void*)l, 16, 0, 17);
}

// stage this wave's k-quarter: 4 x 1KB, no lane duplication (16KB/WG total)
#define STAGE4(SRC) do { \
  glds16((SRC),       &smem[stgw]); \
  glds16((SRC) + 64,  &smem[stgw + 512]); \
  glds16((SRC) + 128, &smem[stgw + 1024]); \
  glds16((SRC) + 192, &smem[stgw + 1536]); \
} while (0)

// K-step: A from swizzle-staged LDS (8 rows, lanes li/li+8 broadcast),
// B (weights) read before the vmcnt wait; dual col-chains share A.
#define KSTEPG(J, VN, WOFF) do { \
  const int k0_ = kqbase + (J) * 32 + koff; \
  short8 b0_ = *(const short8*)&smem[(WOFF) + wb0 + (k0_ ^ sz0)]; \
  short8 b1_ = *(const short8*)&smem[(WOFF) + wb1 + (k0_ ^ sz1)]; \
  WAITV(VN); \
  __builtin_amdgcn_sched_barrier(0); \
  short8 a_ = *(const short8*)&smem[abase + ((J) >> 1) * 512 + (axq ^ (((J) & 1) * 32))]; \
  acc0 = __builtin_amdgcn_mfma_f32_16x16x32_bf16(a_, b0_, acc0, 0, 0, 0); \
  acc1 = __builtin_amdgcn_mfma_f32_16x16x32_bf16(a_, b1_, acc1, 0, 0, 0); \
} while (0)

#define MATVEC8G(WOFF) do { \
  KSTEPG(0,3,WOFF); KSTEPG(1,3,WOFF); KSTEPG(2,2,WOFF); KSTEPG(3,2,WOFF); \
  KSTEPG(4,1,WOFF); KSTEPG(5,1,WOFF); KSTEPG(6,0,WOFF); KSTEPG(7,0,WOFF); \
} while (0)

// per-group barrier (32 WGs): tid0 polls group counter, broadcast, then all
// waves drain stale VMEM so the glds vmcnt ladder is exact.
#define POLL_GRP(TGT) do { \
  if (tid == 0) { \
    while (__hip_atomic_load(gctr, __ATOMIC_RELAXED, __HIP_MEMORY_SCOPE_AGENT) < (TGT)) \
      __builtin_amdgcn_s_sleep(1); \
  } \
  __syncthreads(); \
  WAITV(0); \
  __builtin_amdgcn_sched_barrier(0); \
} while (0)

// ---------------- weight conversion: f32 -> bf16, split h-part / x-part ----
__global__ __launch_bounds__(256) void convert_weights(
    const float* __restrict__ Wz, const float* __restrict__ Wh,
    ushort_t* __restrict__ Wzh, ushort_t* __restrict__ Wzx,
    ushort_t* __restrict__ Whh, ushort_t* __restrict__ Whx)
{
  int j = blockIdx.x;
  const float* W = blockIdx.y ? Wh : Wz;
  ushort_t* Bh = blockIdx.y ? Whh : Wzh;
  ushort_t* Bx = blockIdx.y ? Whx : Wzx;
  const float* row = W + (size_t)j * (HIDDEN + IDIM);
  for (int c = threadIdx.x; c < HIDDEN + IDIM; c += 256) {
    ushort_t v = f2bf(row[c]);
    if (c < HIDDEN) Bh[(size_t)j * HIDDEN + c] = v;
    else            Bx[(size_t)j * IDIM + (c - HIDDEN)] = v;
  }
}

// ---------------- phase 1: Gx = x @ Wx^T + b  (two GEMMs via blockIdx.z) ----
__global__ __launch_bounds__(256) void gx_gemm(
    const float* __restrict__ x,
    const ushort_t* __restrict__ Wzx, const ushort_t* __restrict__ Whx,
    const float* __restrict__ bz, const float* __restrict__ bh,
    float* __restrict__ outZ, float* __restrict__ outR)
{
  const int which = blockIdx.z;
  const ushort_t* W = which ? Whx : Wzx;
  const float* bias = which ? bh : bz;
  float* out = which ? outR : outZ;
  const int m0 = blockIdx.x * 64;
  const int n0 = blockIdx.y * 64;
  __shared__ ushort_t As[64 * 40];
  __shared__ ushort_t Bs[64 * 40];
  const int tid = threadIdx.x;
  const int lane = tid & 63, w4 = tid >> 6;
  const int row = tid >> 2, q = tid & 3;
  f32x4 acc[4] = {{0,0,0,0},{0,0,0,0},{0,0,0,0},{0,0,0,0}};
  for (int kk = 0; kk < IDIM; kk += 32) {
    const float* xs = &x[(size_t)(m0 + row) * IDIM + kk + q * 8];
    float4 f0 = *(const float4*)xs;
    float4 f1 = *(const float4*)(xs + 4);
    short8 av;
    av[0]=f2bf(f0.x); av[1]=f2bf(f0.y); av[2]=f2bf(f0.z); av[3]=f2bf(f0.w);
    av[4]=f2bf(f1.x); av[5]=f2bf(f1.y); av[6]=f2bf(f1.z); av[7]=f2bf(f1.w);
    short8 bv = *(const short8*)&W[(size_t)(n0 + row) * IDIM + kk + q * 8];
    __syncthreads();
    *(short8*)&As[row * 40 + q * 8] = av;
    *(short8*)&Bs[row * 40 + q * 8] = bv;
    __syncthreads();
    short8 af = *(const short8*)&As[(w4 * 16 + (lane & 15)) * 40 + (lane >> 4) * 8];
    #pragma unroll
    for (int c = 0; c < 4; ++c) {
      short8 bf = *(const short8*)&Bs[(c * 16 + (lane & 15)) * 40 + (lane >> 4) * 8];
      acc[c] = __builtin_amdgcn_mfma_f32_16x16x32_bf16(af, bf, acc[c], 0, 0, 0);
    }
  }
  #pragma unroll
  for (int c = 0; c < 4; ++c) {
    int j = n0 + c * 16 + (lane & 15);
    float bv = bias[j];
    #pragma unroll
    for (int r = 0; r < 4; ++r) {
      int m = m0 + w4 * 16 + (lane >> 4) * 4 + r;
      out[(size_t)m * HIDDEN + j] = acc[c][r] + bv;
    }
  }
}

// ---------------- persistent recurrent kernel ------------------------------
// 8 independent row-groups (8 batch rows each, grp = bid&7) x 32 col-slices.
// A-path: 16 coherent glds (4/wave, no duplication, 16KB/WG) -> swizzled
// ds_read A-frags -> MFMA (rows 8-15 of the 16x16 tile are discarded dups).
__global__ __launch_bounds__(256) void gru_persist(
    const ushort_t* __restrict__ Wzh, const ushort_t* __restrict__ Whh,
    float* __restrict__ H, float* __restrict__ Z, float* __restrict__ R,
    u64* __restrict__ h_buf, u64* __restrict__ ghb, int* __restrict__ ctrs)
{
  extern __shared__ ushort_t smem[];
  const int tid = threadIdx.x;
  const int lane = tid & 63, wv = tid >> 6;
  const int grp = blockIdx.x & 7, slot = blockIdx.x >> 3;
  const int rbase = grp * 8;             // batch-row block (8 rows)
  const int jbase = slot * 32;           // output-column block
  int* gctr = ctrs + grp * 32;           // 128B-spaced group counters
  const ushort_t* hgu = (const ushort_t*)h_buf;
  const ushort_t* ggu = (const ushort_t*)ghb;

  // stage weight slices (row-XOR swizzle k ^= (row&7)<<3)
  for (int c = tid; c < 32 * 128; c += 256) {
    int row = c >> 7, k8 = (c & 127) * 8;
    int dst = row * 1024 + (k8 ^ ((row & 7) << 3));
    *(short8*)&smem[dst]         = *(const short8*)&Wzh[(size_t)(jbase + row) * 1024 + k8];
    *(short8*)&smem[32768 + dst] = *(const short8*)&Whh[(size_t)(jbase + row) * 1024 + k8];
  }
  __syncthreads();   // weights ready (h0 + ctrs zeroed by host memset)

  // H[0] = 0 for this WG's 8x32 block (background)
  if (tid < 64) {
    float4 z4 = {0.f, 0.f, 0.f, 0.f};
    *(float4*)&H[(size_t)(rbase + (tid >> 3)) * 1024 + jbase + (tid & 7) * 4] = z4;
  }

  // wave decomposition: wv = k-quarter; epilogue chains on waves 0,1
  const int li = lane & 15, q4 = lane >> 4;
  const int kqbase = wv * 256;
  const int koff = q4 * 8;
  const int wb0 = li * 1024,     wb1 = (16 + li) * 1024;
  const int sz0 = (li & 7) << 3, sz1 = ((16 + li) & 7) << 3;
  const int m0 = q4 * 4;                       // valid rows when q4<2
  const int col = jbase + (wv & 1) * 16 + li;  // epilogue column (waves 0,1)
  // glds source: row = rbase + (lane>>3); inverse-swizzled chunk (m173 pattern)
  const int srow = lane >> 3, schk = (lane & 7) ^ srow;
  const ushort_t* srcAh = hgu + (size_t)(rbase + srow) * 1024 + kqbase + schk * 8;
  const ushort_t* srcAg = ggu + (size_t)(rbase + srow) * 1024 + kqbase + schk * 8;
  const int stgw = STG + wv * 2048;            // wave staging base (ushort idx)
  // A-frag read: row rr=li&7 (li/li+8 broadcast), swizzled chunk
  const int abase = stgw + (li & 7) * 64;
  const int axq = (q4 ^ (li & 7)) * 8;
  // broadcast-store mapping (tid<64): row = tid>>3, 4-col u64 chunk tid&7
  const int bidx = (rbase + (tid >> 3)) * 256 + slot * 8 + (tid & 7);   // u64 idx
  const int scrt_rd = SCRT + (tid >> 3) * 40 + (tid & 7) * 4;
  // SCRR slots: [chain 0/1][quarter wv][lane] x 16B
  const int rr0 = SCRR + ((0 * 4 + wv) * 64 + lane) * 8;
  const int rr1 = SCRR + ((1 * 4 + wv) * 64 + lane) * 8;
  const int rrc = SCRR + ((wv & 1) * 4 * 64 + lane) * 8;   // epilogue chain base

  float hreg[4] = {0.f, 0.f, 0.f, 0.f};
  float g[4], hn[4], gz[4], gh[4];

  for (int t = 0; t < T_STEPS; ++t) {
    const size_t zoff = (size_t)t * BH;

    // prefetch BOTH gate inputs before POLL-A (drain window = detect time;
    // POLL-B then sees a clean vmcnt)
    if (wv < 2 && q4 < 2)
      #pragma unroll
      for (int r = 0; r < 4; ++r) {
        gz[r] = Z[zoff + (size_t)(rbase + m0 + r) * 1024 + col];
        gh[r] = R[zoff + (size_t)(rbase + m0 + r) * 1024 + col];
      }

    // ---- phase A: z-gate -------------------------------------------------
    POLL_GRP(64 * t);                 // group finished h(t) stores

    f32x4 acc0 = {0, 0, 0, 0}, acc1 = {0, 0, 0, 0};
    STAGE4(srcAh);
    MATVEC8G(0);

    *(f32x4*)&smem[rr0] = acc0;
    *(f32x4*)&smem[rr1] = acc1;
    __syncthreads();
    if (wv < 2) {
      f32x4 s = *(const f32x4*)&smem[rrc];
      #pragma unroll
      for (int q = 1; q < 4; ++q) {
        f32x4 o = *(const f32x4*)&smem[rrc + q * 64 * 8];
        #pragma unroll
        for (int r = 0; r < 4; ++r) s[r] += o[r];
      }
      #pragma unroll
      for (int r = 0; r < 4; ++r) g[r] = sigmoid_f(s[r] + gz[r]);
      if (q4 < 2)
        #pragma unroll
        for (int r = 0; r < 4; ++r)
          smem[SCRT + (m0 + r) * 40 + (wv & 1) * 16 + li] = f2bf(g[r] * hreg[r]);
    }
    __syncthreads();
    if (tid < 64) {
      u64 v = *(const u64*)&smem[scrt_rd];
      __hip_atomic_store(ghb + bidx, v, __ATOMIC_RELAXED, __HIP_MEMORY_SCOPE_AGENT);
    }
    WAITV(0);                          // g*h stores acked at LLC
    __syncthreads();
    if (tid == 0)
      __hip_atomic_fetch_add(gctr, 1, __ATOMIC_RELAXED, __HIP_MEMORY_SCOPE_AGENT);

    // ---- phase B: candidate ---------------------------------------------
    POLL_GRP(64 * t + 32);            // group finished g*h stores

    acc0 = (f32x4){0, 0, 0, 0}; acc1 = (f32x4){0, 0, 0, 0};
    STAGE4(srcAg);
    MATVEC8G(32768);

    *(f32x4*)&smem[rr0] = acc0;
    *(f32x4*)&smem[rr1] = acc1;
    __syncthreads();
    if (wv < 2) {
      f32x4 s = *(const f32x4*)&smem[rrc];
      #pragma unroll
      for (int q = 1; q < 4; ++q) {
        f32x4 o = *(const f32x4*)&smem[rrc + q * 64 * 8];
        #pragma unroll
        for (int r = 0; r < 4; ++r) s[r] += o[r];
      }
      #pragma unroll
      for (int r = 0; r < 4; ++r) {
        float cand = tanh_f(s[r] + gh[r]);
        hn[r] = (1.f - g[r]) * hreg[r] + g[r] * cand;
        hreg[r] = hn[r];
      }
      if (q4 < 2)
        #pragma unroll
        for (int r = 0; r < 4; ++r)
          smem[SCRT + (m0 + r) * 40 + (wv & 1) * 16 + li] = f2bf(hn[r]);
    }
    __syncthreads();
    if (tid < 64) {
      u64 v = *(const u64*)&smem[scrt_rd];
      __hip_atomic_store(h_buf + bidx, v, __ATOMIC_RELAXED, __HIP_MEMORY_SCOPE_AGENT);
    }
    WAITV(0);                          // h stores acked at LLC
    __syncthreads();
    if (tid == 0)
      __hip_atomic_fetch_add(gctr, 1, __ATOMIC_RELAXED, __HIP_MEMORY_SCOPE_AGENT);

    // bulk outputs (epilogue lanes; drain in background during next poll)
    if (wv < 2 && q4 < 2) {
      const size_t hoff = (size_t)(t + 1) * BH;
      #pragma unroll
      for (int r = 0; r < 4; ++r) {
        const size_t rowo = (size_t)(rbase + m0 + r) * 1024 + col;
        Z[zoff + rowo] = g[r];
        R[zoff + rowo] = g[r];
        H[hoff + rowo] = hn[r];
      }
    }
  }
}

// ---------------- host launcher -------------------------------------------
extern "C" void kernel_launch(void* const* d_in, const int* in_sizes, int n_in,
                              void* d_out, int out_size, void* d_ws, size_t ws_size,
                              hipStream_t stream) {
  (void)in_sizes; (void)n_in; (void)out_size; (void)ws_size;
  const float* x  = (const float*)d_in[0];
  const float* Wz = (const float*)d_in[1];
  const float* bz = (const float*)d_in[2];
  const float* Wh = (const float*)d_in[3];
  const float* bh = (const float*)d_in[4];

  float* H = (float*)d_out;
  float* Z = H + (size_t)(T_STEPS + 1) * BH;
  float* R = Z + (size_t)T_STEPS * BH;

  char* ws = (char*)d_ws;
  int*      ctrs  = (int*)ws;                                   // 8 group ctrs, 128B apart
  u64*      h_buf = (u64*)(ws + 16384);                         // 128 KB linear bf16
  u64*      ghb   = (u64*)(ws + 16384 + 131072);                // 128 KB linear bf16
  ushort_t* Wzh   = (ushort_t*)(ws + 16384 + 2 * 131072);       // 2 MB
  ushort_t* Whh   = Wzh + (size_t)HIDDEN * HIDDEN;              // 2 MB
  ushort_t* Wzx   = Whh + (size_t)HIDDEN * HIDDEN;              // 1 MB
  ushort_t* Whx   = Wzx + (size_t)HIDDEN * IDIM;                // 1 MB

  hipFuncSetAttribute((const void*)gru_persist,
                      hipFuncAttributeMaxDynamicSharedMemorySize, 156416);

  hipMemsetAsync(ctrs, 0, 16384, stream);
  hipMemsetAsync(h_buf, 0, 131072, stream);   // h0 = 0 (kernel-boundary visible)
  convert_weights<<<dim3(HIDDEN, 2), 256, 0, stream>>>(Wz, Wh, Wzh, Wzx, Whh, Whx);
  gx_gemm<<<dim3(T_STEPS * BATCH / 64, HIDDEN / 64, 2), 256, 0, stream>>>(
      x, Wzx, Whx, bz, bh, Z, R);
  gru_persist<<<NWGP, 256, 156416, stream>>>(Wzh, Whh, H, Z, R, h_buf, ghb, ctrs);
}

// Round 13
// 2346.156 us; speedup vs baseline: 3.0427x; 1.0235x over previous
//
#include <hip/hip_runtime.h>
#include <cstdint>

typedef unsigned short ushort_t;
typedef __attribute__((ext_vector_type(8))) short short8;
typedef __attribute__((ext_vector_type(4))) float f32x4;
typedef unsigned long long u64;

#define T_STEPS 512
#define BATCH   64
#define IDIM    512
#define HIDDEN  1024
#define NWGP    256         // 8 row-groups (bid&7) x 32 col-slices (bid>>3)
#define BH      (BATCH*HIDDEN)   // 65536
// LDS (ushort idx): [0,32768) Wz slice, [32768,65536) Wh slice,
// [65536,73728) STG A-staging (4 waves x 2KB-ushort), [73728,77824) SCRR.
// Total 77824 ushorts = 155648 B.
#define STG     65536
#define SCRR    73728

__device__ __forceinline__ ushort_t f2bf(float f) {
  unsigned int x = __float_as_uint(f);
  unsigned int r = (x + 0x7fffu + ((x >> 16) & 1u)) >> 16;
  return (ushort_t)r;
}
__device__ __forceinline__ float sigmoid_f(float x) { return 1.f / (1.f + __expf(-x)); }
__device__ __forceinline__ float tanh_f(float x)    { return 1.f - 2.f / (1.f + __expf(2.f * x)); }

#define WAITV(N) asm volatile("s_waitcnt vmcnt(" #N ")" ::: "memory")

// coherent global->LDS direct load, 16B/lane, aux=17 (sc0|sc1): bypass L1+L2,
// read at LLC (R4-proven). Dest is wave-uniform base + lane*16 (linear).
__device__ __forceinline__ void glds16(const ushort_t* g, ushort_t* l) {
  __builtin_amdgcn_global_load_lds(
      (const __attribute__((address_space(1))) void*)g,
      (__attribute__((address_space(3))) void*)l, 16, 0, 17);
}

// stage this wave's k-quarter: 4 x 1KB, no lane duplication (16KB/WG total)
#define STAGE4(SRC) do { \
  glds16((SRC),       &smem[stgw]); \
  glds16((SRC) + 64,  &smem[stgw + 512]); \
  glds16((SRC) + 128, &smem[stgw + 1024]); \
  glds16((SRC) + 192, &smem[stgw + 1536]); \
} while (0)

// K-step with SWAPPED operands: D[j, m] so each lane holds 4 consecutive
// output cols for one batch row (direct 8B broadcast store, no transpose).
#define KSTEPG(J, VN, WOFF) do { \
  const int k0_ = kqbase + (J) * 32 + koff; \
  short8 b0_ = *(const short8*)&smem[(WOFF) + wb0 + (k0_ ^ sz0)]; \
  short8 b1_ = *(const short8*)&smem[(WOFF) + wb1 + (k0_ ^ sz1)]; \
  WAITV(VN); \
  __builtin_amdgcn_sched_barrier(0); \
  short8 a_ = *(const short8*)&smem[abase + ((J) >> 1) * 512 + (axq ^ (((J) & 1) * 32))]; \
  acc0 = __builtin_amdgcn_mfma_f32_16x16x32_bf16(b0_, a_, acc0, 0, 0, 0); \
  acc1 = __builtin_amdgcn_mfma_f32_16x16x32_bf16(b1_, a_, acc1, 0, 0, 0); \
} while (0)

#define MATVEC8G(WOFF) do { \
  KSTEPG(0,3,WOFF); KSTEPG(1,3,WOFF); KSTEPG(2,2,WOFF); KSTEPG(3,2,WOFF); \
  KSTEPG(4,1,WOFF); KSTEPG(5,1,WOFF); KSTEPG(6,0,WOFF); KSTEPG(7,0,WOFF); \
} while (0)

// per-group barrier (32 WGs): tid0 polls group counter, broadcast, then all
// waves drain stale VMEM so the glds vmcnt ladder is exact.
#define POLL_GRP(TGT) do { \
  if (tid == 0) { \
    while (__hip_atomic_load(gctr, __ATOMIC_RELAXED, __HIP_MEMORY_SCOPE_AGENT) < (TGT)) \
      __builtin_amdgcn_s_sleep(1); \
  } \
  __syncthreads(); \
  WAITV(0); \
  __builtin_amdgcn_sched_barrier(0); \
} while (0)

// ---------------- weight conversion: f32 -> bf16, split h-part / x-part ----
__global__ __launch_bounds__(256) void convert_weights(
    const float* __restrict__ Wz, const float* __restrict__ Wh,
    ushort_t* __restrict__ Wzh, ushort_t* __restrict__ Wzx,
    ushort_t* __restrict__ Whh, ushort_t* __restrict__ Whx)
{
  int j = blockIdx.x;
  const float* W = blockIdx.y ? Wh : Wz;
  ushort_t* Bh = blockIdx.y ? Whh : Wzh;
  ushort_t* Bx = blockIdx.y ? Whx : Wzx;
  const float* row = W + (size_t)j * (HIDDEN + IDIM);
  for (int c = threadIdx.x; c < HIDDEN + IDIM; c += 256) {
    ushort_t v = f2bf(row[c]);
    if (c < HIDDEN) Bh[(size_t)j * HIDDEN + c] = v;
    else            Bx[(size_t)j * IDIM + (c - HIDDEN)] = v;
  }
}

// ---------------- phase 1: fused Gxz+Gxh GEMM (shared A-tile) ---------------
__global__ __launch_bounds__(256) void gx_gemm2(
    const float* __restrict__ x,
    const ushort_t* __restrict__ Wzx, const ushort_t* __restrict__ Whx,
    const float* __restrict__ bz, const float* __restrict__ bh,
    float* __restrict__ outZ, float* __restrict__ outR)
{
  const int m0 = blockIdx.x * 64;
  const int n0 = blockIdx.y * 64;
  __shared__ ushort_t As[64 * 40];
  __shared__ ushort_t Bzs[64 * 40];
  __shared__ ushort_t Bhs[64 * 40];
  const int tid = threadIdx.x;
  const int lane = tid & 63, w4 = tid >> 6;
  const int row = tid >> 2, q = tid & 3;
  f32x4 accz[4] = {{0,0,0,0},{0,0,0,0},{0,0,0,0},{0,0,0,0}};
  f32x4 acch[4] = {{0,0,0,0},{0,0,0,0},{0,0,0,0},{0,0,0,0}};
  for (int kk = 0; kk < IDIM; kk += 32) {
    const float* xs = &x[(size_t)(m0 + row) * IDIM + kk + q * 8];
    float4 f0 = *(const float4*)xs;
    float4 f1 = *(const float4*)(xs + 4);
    short8 av;
    av[0]=f2bf(f0.x); av[1]=f2bf(f0.y); av[2]=f2bf(f0.z); av[3]=f2bf(f0.w);
    av[4]=f2bf(f1.x); av[5]=f2bf(f1.y); av[6]=f2bf(f1.z); av[7]=f2bf(f1.w);
    short8 bzv = *(const short8*)&Wzx[(size_t)(n0 + row) * IDIM + kk + q * 8];
    short8 bhv = *(const short8*)&Whx[(size_t)(n0 + row) * IDIM + kk + q * 8];
    __syncthreads();
    *(short8*)&As[row * 40 + q * 8]  = av;
    *(short8*)&Bzs[row * 40 + q * 8] = bzv;
    *(short8*)&Bhs[row * 40 + q * 8] = bhv;
    __syncthreads();
    short8 af = *(const short8*)&As[(w4 * 16 + (lane & 15)) * 40 + (lane >> 4) * 8];
    #pragma unroll
    for (int c = 0; c < 4; ++c) {
      short8 bzf = *(const short8*)&Bzs[(c * 16 + (lane & 15)) * 40 + (lane >> 4) * 8];
      short8 bhf = *(const short8*)&Bhs[(c * 16 + (lane & 15)) * 40 + (lane >> 4) * 8];
      accz[c] = __builtin_amdgcn_mfma_f32_16x16x32_bf16(af, bzf, accz[c], 0, 0, 0);
      acch[c] = __builtin_amdgcn_mfma_f32_16x16x32_bf16(af, bhf, acch[c], 0, 0, 0);
    }
  }
  #pragma unroll
  for (int c = 0; c < 4; ++c) {
    int j = n0 + c * 16 + (lane & 15);
    float bzv = bz[j], bhv = bh[j];
    #pragma unroll
    for (int r = 0; r < 4; ++r) {
      int m = m0 + w4 * 16 + (lane >> 4) * 4 + r;
      outZ[(size_t)m * HIDDEN + j] = accz[c][r] + bzv;
      outR[(size_t)m * HIDDEN + j] = acch[c][r] + bhv;
    }
  }
}

// ---------------- persistent recurrent kernel ------------------------------
// 8 independent row-groups (8 batch rows each, grp = bid&7) x 32 col-slices.
// A-path: 16 coherent glds (4/wave, no duplication, 16KB/WG). MFMA operands
// SWAPPED so D[j,m]: epilogue lane owns (row li, 4 consecutive cols) ->
// direct 8B broadcast store + float4 bulk outputs (no LDS transpose).
__global__ __launch_bounds__(256) void gru_persist(
    const ushort_t* __restrict__ Wzh, const ushort_t* __restrict__ Whh,
    float* __restrict__ H, float* __restrict__ Z, float* __restrict__ R,
    u64* __restrict__ h_buf, u64* __restrict__ ghb, int* __restrict__ ctrs)
{
  extern __shared__ ushort_t smem[];
  const int tid = threadIdx.x;
  const int lane = tid & 63, wv = tid >> 6;
  const int grp = blockIdx.x & 7, slot = blockIdx.x >> 3;
  const int rbase = grp * 8;             // batch-row block (8 rows)
  const int jbase = slot * 32;           // output-column block
  int* gctr = ctrs + grp * 32;           // 128B-spaced group counters
  const ushort_t* hgu = (const ushort_t*)h_buf;
  const ushort_t* ggu = (const ushort_t*)ghb;

  // stage weight slices (row-XOR swizzle k ^= (row&7)<<3)
  for (int c = tid; c < 32 * 128; c += 256) {
    int row = c >> 7, k8 = (c & 127) * 8;
    int dst = row * 1024 + (k8 ^ ((row & 7) << 3));
    *(short8*)&smem[dst]         = *(const short8*)&Wzh[(size_t)(jbase + row) * 1024 + k8];
    *(short8*)&smem[32768 + dst] = *(const short8*)&Whh[(size_t)(jbase + row) * 1024 + k8];
  }
  __syncthreads();   // weights ready (h0 + ctrs zeroed by host memset)

  // H[0] = 0 for this WG's 8x32 block (background)
  if (tid < 64) {
    float4 z4 = {0.f, 0.f, 0.f, 0.f};
    *(float4*)&H[(size_t)(rbase + (tid >> 3)) * 1024 + jbase + (tid & 7) * 4] = z4;
  }

  // wave decomposition: wv = k-quarter; epilogue on waves 0,1 (chain = wv)
  const int li = lane & 15, q4 = lane >> 4;
  const int kqbase = wv * 256;
  const int koff = q4 * 8;
  const int wb0 = li * 1024,     wb1 = (16 + li) * 1024;
  const int sz0 = (li & 7) << 3, sz1 = ((16 + li) & 7) << 3;
  // glds source: row = rbase + (lane>>3); inverse-swizzled chunk (m173 pattern)
  const int srow = lane >> 3, schk = (lane & 7) ^ srow;
  const ushort_t* srcAh = hgu + (size_t)(rbase + srow) * 1024 + kqbase + schk * 8;
  const ushort_t* srcAg = ggu + (size_t)(rbase + srow) * 1024 + kqbase + schk * 8;
  const int stgw = STG + wv * 2048;            // wave staging base (ushort idx)
  // A-frag read: row rr=li&7 (li/li+8 broadcast), swizzled chunk
  const int abase = stgw + (li & 7) * 64;
  const int axq = (q4 ^ (li & 7)) * 8;
  // epilogue mapping (waves 0,1; valid rows li<8): row = rbase+li,
  // cols = jbase + wv*16 + q4*4 .. +3  (8B-aligned chunk)
  const bool epi = (wv < 2) && (li < 8);
  const int erow = rbase + li;
  const int ecol = jbase + (wv & 1) * 16 + q4 * 4;
  const int gidx = (erow * 1024 + ecol) >> 2;            // u64 exchange idx
  // SCRR slots: [chain 0/1][quarter wv][lane] x 16B
  const int rr0 = SCRR + ((0 * 4 + wv) * 64 + lane) * 8;
  const int rr1 = SCRR + ((1 * 4 + wv) * 64 + lane) * 8;
  const int rrc = SCRR + ((wv & 1) * 4 * 64 + lane) * 8; // epilogue chain base

  float hreg[4] = {0.f, 0.f, 0.f, 0.f};    // h[erow][ecol..ecol+3]
  float g[4], hn[4], gz[4], gh[4];

  for (int t = 0; t < T_STEPS; ++t) {
    const size_t zoff = (size_t)t * BH;

    // prefetch BOTH gate inputs before POLL-A (drain window = detect time)
    if (epi) {
      f32x4 z4 = *(const f32x4*)&Z[zoff + (size_t)erow * 1024 + ecol];
      f32x4 r4 = *(const f32x4*)&R[zoff + (size_t)erow * 1024 + ecol];
      #pragma unroll
      for (int r = 0; r < 4; ++r) { gz[r] = z4[r]; gh[r] = r4[r]; }
    }

    // ---- phase A: z-gate -------------------------------------------------
    POLL_GRP(64 * t);                 // group finished h(t) stores

    f32x4 acc0 = {0, 0, 0, 0}, acc1 = {0, 0, 0, 0};
    STAGE4(srcAh);
    MATVEC8G(0);

    *(f32x4*)&smem[rr0] = acc0;
    *(f32x4*)&smem[rr1] = acc1;
    __syncthreads();
    if (epi) {
      f32x4 s = *(const f32x4*)&smem[rrc];
      #pragma unroll
      for (int q = 1; q < 4; ++q) {
        f32x4 o = *(const f32x4*)&smem[rrc + q * 64 * 8];
        #pragma unroll
        for (int r = 0; r < 4; ++r) s[r] += o[r];
      }
      #pragma unroll
      for (int r = 0; r < 4; ++r) g[r] = sigmoid_f(s[r] + gz[r]);
      u64 v = (u64)f2bf(g[0] * hreg[0])
            | ((u64)f2bf(g[1] * hreg[1]) << 16)
            | ((u64)f2bf(g[2] * hreg[2]) << 32)
            | ((u64)f2bf(g[3] * hreg[3]) << 48);
      __hip_atomic_store(ghb + gidx, v, __ATOMIC_RELAXED, __HIP_MEMORY_SCOPE_AGENT);
    }
    WAITV(0);                          // g*h stores acked at LLC
    __syncthreads();
    if (tid == 0)
      __hip_atomic_fetch_add(gctr, 1, __ATOMIC_RELAXED, __HIP_MEMORY_SCOPE_AGENT);

    // ---- phase B: candidate ---------------------------------------------
    POLL_GRP(64 * t + 32);            // group finished g*h stores

    acc0 = (f32x4){0, 0, 0, 0}; acc1 = (f32x4){0, 0, 0, 0};
    STAGE4(srcAg);
    MATVEC8G(32768);

    *(f32x4*)&smem[rr0] = acc0;
    *(f32x4*)&smem[rr1] = acc1;
    __syncthreads();
    if (epi) {
      f32x4 s = *(const f32x4*)&smem[rrc];
      #pragma unroll
      for (int q = 1; q < 4; ++q) {
        f32x4 o = *(const f32x4*)&smem[rrc + q * 64 * 8];
        #pragma unroll
        for (int r = 0; r < 4; ++r) s[r] += o[r];
      }
      #pragma unroll
      for (int r = 0; r < 4; ++r) {
        float cand = tanh_f(s[r] + gh[r]);
        hn[r] = (1.f - g[r]) * hreg[r] + g[r] * cand;
        hreg[r] = hn[r];
      }
      u64 v = (u64)f2bf(hn[0])
            | ((u64)f2bf(hn[1]) << 16)
            | ((u64)f2bf(hn[2]) << 32)
            | ((u64)f2bf(hn[3]) << 48);
      __hip_atomic_store(h_buf + gidx, v, __ATOMIC_RELAXED, __HIP_MEMORY_SCOPE_AGENT);
    }
    WAITV(0);                          // h stores acked at LLC
    __syncthreads();
    if (tid == 0)
      __hip_atomic_fetch_add(gctr, 1, __ATOMIC_RELAXED, __HIP_MEMORY_SCOPE_AGENT);

    // bulk outputs (drain in background during next poll) — float4 stores
    if (epi) {
      const size_t hoff = (size_t)(t + 1) * BH;
      const size_t rowo = (size_t)erow * 1024 + ecol;
      float4 gv = {g[0], g[1], g[2], g[3]};
      float4 hv = {hn[0], hn[1], hn[2], hn[3]};
      *(float4*)&Z[zoff + rowo] = gv;
      *(float4*)&R[zoff + rowo] = gv;
      *(float4*)&H[hoff + rowo] = hv;
    }
  }
}

// ---------------- host launcher -------------------------------------------
extern "C" void kernel_launch(void* const* d_in, const int* in_sizes, int n_in,
                              void* d_out, int out_size, void* d_ws, size_t ws_size,
                              hipStream_t stream) {
  (void)in_sizes; (void)n_in; (void)out_size; (void)ws_size;
  const float* x  = (const float*)d_in[0];
  const float* Wz = (const float*)d_in[1];
  const float* bz = (const float*)d_in[2];
  const float* Wh = (const float*)d_in[3];
  const float* bh = (const float*)d_in[4];

  float* H = (float*)d_out;
  float* Z = H + (size_t)(T_STEPS + 1) * BH;
  float* R = Z + (size_t)T_STEPS * BH;

  char* ws = (char*)d_ws;
  int*      ctrs  = (int*)ws;                                   // 8 group ctrs, 128B apart
  u64*      h_buf = (u64*)(ws + 16384);                         // 128 KB linear bf16
  u64*      ghb   = (u64*)(ws + 16384 + 131072);                // 128 KB linear bf16
  ushort_t* Wzh   = (ushort_t*)(ws + 16384 + 2 * 131072);       // 2 MB
  ushort_t* Whh   = Wzh + (size_t)HIDDEN * HIDDEN;              // 2 MB
  ushort_t* Wzx   = Whh + (size_t)HIDDEN * HIDDEN;              // 1 MB
  ushort_t* Whx   = Wzx + (size_t)HIDDEN * IDIM;                // 1 MB

  hipFuncSetAttribute((const void*)gru_persist,
                      hipFuncAttributeMaxDynamicSharedMemorySize, 155648);

  hipMemsetAsync(ctrs, 0, 16384, stream);
  hipMemsetAsync(h_buf, 0, 131072, stream);   // h0 = 0 (kernel-boundary visible)
  convert_weights<<<dim3(HIDDEN, 2), 256, 0, stream>>>(Wz, Wh, Wzh, Wzx, Whh, Whx);
  gx_gemm2<<<dim3(T_STEPS * BATCH / 64, HIDDEN / 64), 256, 0, stream>>>(
      x, Wzx, Whx, bz, bh, Z, R);
  gru_persist<<<NWGP, 256, 155648, stream>>>(Wzh, Whh, H, Z, R, h_buf, ghb, ctrs);
}